// Round 7
// baseline (673.550 us; speedup 1.0000x reference)
//
#include <hip/hip_runtime.h>
#include <math.h>
#include <stdint.h>

// Problem constants (fixed by the reference)
#define L_SEQ   4096
#define DI      4096   // d_inner
#define RNK     128    // dt_rank
#define NS      16     // d_state
#define NCOL    160    // dt_rank + 2*d_state
#define GCH     32     // scan chunks
#define CLEN    128    // L_SEQ / GCH
#define KSPLIT  16     // gemm1 K slices

// Buffers:
//   d_out (64 MB) triple-duty: gemm1 partials (16 x 2.6 MB) -> delta [L,D] -> output [L,D]
//   ws: [0, 655360) final dbc [L,160]; [655360, +4194304) chunk partials [G][32][D]
#define DBC_SLICE 655360
#define PART_OFF  655360

__device__ __forceinline__ float fast_exp2(float v) {
#if __has_builtin(__builtin_amdgcn_exp2f)
  return __builtin_amdgcn_exp2f(v);
#else
  return exp2f(v);
#endif
}

// async global->LDS, 16B per lane; LDS dest is wave-uniform base + lane*16 (HW).
typedef __attribute__((address_space(3))) char* lds_p_t;
typedef const __attribute__((address_space(1))) char* glb_p_t;
__device__ __forceinline__ void gll16(const float* g, float* l) {
  __builtin_amdgcn_global_load_lds((glb_p_t)(uintptr_t)(const void*)g,
                                   (lds_p_t)(uintptr_t)(void*)l, 16, 0, 0);
}

// ---------------- GEMM1: dbc[l,j] = sum_k x[l,k] * W_in[j,k] ----------------
// grid 1024: bx>>4 = m-tile (64 rows), bx&15 = K slice (256 K each, 8 chunks of 32).
__global__ __launch_bounds__(256) void gemm1_kernel(const float* __restrict__ x,
                                                    const float* __restrict__ Win,
                                                    float* __restrict__ parts) {
  __shared__ float xs[64][36];
  __shared__ float wsh[160][36];
  const int t  = threadIdx.x;
  const int tx = t & 15, ty = t >> 4;
  const int mt = blockIdx.x >> 4;
  const int ks = blockIdx.x & 15;
  const int row0 = mt * 64;
  const int kbase0 = ks * 256;

  float acc[4][10];
#pragma unroll
  for (int r = 0; r < 4; ++r)
#pragma unroll
    for (int c = 0; c < 10; ++c) acc[r][c] = 0.f;

  for (int kc = 0; kc < 8; ++kc) {
    const int kb = kbase0 + kc * 32;
#pragma unroll
    for (int i = 0; i < 2; ++i) {            // x tile: 64 rows x 32 k
      int f = t + i * 256;
      int r = f >> 3, c4 = (f & 7) * 4;
      *(float4*)&xs[r][c4] = *(const float4*)&x[(row0 + r) * 4096 + kb + c4];
    }
#pragma unroll
    for (int i = 0; i < 5; ++i) {            // W tile: 160 rows x 32 k
      int f = t + i * 256;
      int r = f >> 3, c4 = (f & 7) * 4;
      *(float4*)&wsh[r][c4] = *(const float4*)&Win[r * 4096 + kb + c4];
    }
    __syncthreads();
#pragma unroll
    for (int kk = 0; kk < 8; ++kk) {
      float4 xv[4];
#pragma unroll
      for (int r = 0; r < 4; ++r) xv[r] = *(float4*)&xs[ty * 4 + r][kk * 4];
#pragma unroll
      for (int c = 0; c < 10; ++c) {
        float4 wv = *(float4*)&wsh[tx + 16 * c][kk * 4];
#pragma unroll
        for (int r = 0; r < 4; ++r) {
          acc[r][c] = fmaf(xv[r].x, wv.x, acc[r][c]);
          acc[r][c] = fmaf(xv[r].y, wv.y, acc[r][c]);
          acc[r][c] = fmaf(xv[r].z, wv.z, acc[r][c]);
          acc[r][c] = fmaf(xv[r].w, wv.w, acc[r][c]);
        }
      }
    }
    __syncthreads();
  }
  float* outp = parts + ks * DBC_SLICE;
#pragma unroll
  for (int r = 0; r < 4; ++r)
#pragma unroll
    for (int c = 0; c < 10; ++c)
      outp[(row0 + ty * 4 + r) * NCOL + tx + 16 * c] = acc[r][c];
}

// ---------------- reduce the 16 K-slices (in d_out scratch) into ws dbc ----------------
__global__ __launch_bounds__(256) void reduce_dbc_kernel(const float* __restrict__ parts,
                                                         float* __restrict__ dbc) {
  const int i = (blockIdx.x * 256 + threadIdx.x) * 4;  // grid 640 -> covers 655360
  float4 a = *(const float4*)&parts[i];
#pragma unroll
  for (int s = 1; s < KSPLIT; ++s) {
    float4 b = *(const float4*)&parts[(size_t)s * DBC_SLICE + i];
    a.x += b.x; a.y += b.y; a.z += b.z; a.w += b.w;
  }
  *(float4*)&dbc[i] = a;
}

// ---- GEMM2 + softplus: delta[l,d] = softplus(sum_k dbc[l,k]*W_delta[d,k]) ----
// grid 1024 (32x32 tiles of 128x128), block 256, thread 8x8.
// Double-buffered async staging (global_load_lds 16B), XOR-swizzled layout:
//   LDS slot (row, j) holds global (row, j ^ (row&7));  read with kq = kk ^ (row&7).
//   -> av: 4 distinct bank-quads (conflict-free); bv: 2-way (free).
// 64 KB LDS -> 2 blocks/CU; ONE barrier per K-chunk, prefetch issued before compute.
__device__ __forceinline__ void g2_stage(const float* __restrict__ dbc,
                                         const float* __restrict__ Wd,
                                         float* smem, int buf, int kb,
                                         int mt, int nt, int w, int lr, int swz) {
  float* Ab = smem + buf * 8192;
  float* Bb = Ab + 4096;
#pragma unroll
  for (int q = 0; q < 4; ++q) {
    const int row = 32 * w + 8 * q + lr;                 // 0..127, per-lane
    gll16(&dbc[(mt * 128 + row) * NCOL + kb + swz * 4],  // per-lane global src
          &Ab[(32 * w + 8 * q) * 32]);                   // wave-uniform LDS base
    gll16(&Wd[(nt * 128 + row) * RNK + kb + swz * 4],
          &Bb[(32 * w + 8 * q) * 32]);
  }
}

__global__ __launch_bounds__(256) void gemm2_kernel(const float* __restrict__ dbc,
                                                    const float* __restrict__ Wd,
                                                    float* __restrict__ delta_out) {
  __shared__ float smem[16384];   // [buf0 A|B][buf1 A|B], 4096 floats each, 64 KB
  const int t  = threadIdx.x;
  const int tx = t & 15, ty = t >> 4;
  const int w  = t >> 6;          // wave 0..3
  const int l  = t & 63;
  const int lr = l >> 3;          // lane row-in-group 0..7
  const int lj = l & 7;           // lane kquad 0..7
  const int swz = lj ^ lr;        // source kquad for XOR layout ((row&7)==lr)
  const int mt = blockIdx.x & 31, nt = blockIdx.x >> 5;
  const int sa = ty & 7;          // (A row)&7 for rows ty+16r
  const int sb = tx & 7;          // (B row)&7 for rows tx+16c

  float acc[8][8];
#pragma unroll
  for (int r = 0; r < 8; ++r)
#pragma unroll
    for (int c = 0; c < 8; ++c) acc[r][c] = 0.f;

  g2_stage(dbc, Wd, smem, 0, 0, mt, nt, w, lr, swz);
  __syncthreads();

  for (int kc = 0; kc < 4; ++kc) {
    if (kc < 3) g2_stage(dbc, Wd, smem, (kc + 1) & 1, (kc + 1) * 32, mt, nt, w, lr, swz);
    const float* Ab = smem + (kc & 1) * 8192;
    const float* Bb = Ab + 4096;
#pragma unroll
    for (int kk = 0; kk < 8; ++kk) {
      float4 av[8];
#pragma unroll
      for (int r = 0; r < 8; ++r)
        av[r] = *(const float4*)&Ab[(ty + 16 * r) * 32 + ((kk ^ sa) << 2)];
#pragma unroll
      for (int c = 0; c < 8; ++c) {
        float4 bv = *(const float4*)&Bb[(tx + 16 * c) * 32 + ((kk ^ sb) << 2)];
#pragma unroll
        for (int r = 0; r < 8; ++r) {
          acc[r][c] = fmaf(av[r].x, bv.x, acc[r][c]);
          acc[r][c] = fmaf(av[r].y, bv.y, acc[r][c]);
          acc[r][c] = fmaf(av[r].z, bv.z, acc[r][c]);
          acc[r][c] = fmaf(av[r].w, bv.w, acc[r][c]);
        }
      }
    }
    if (kc < 3) __syncthreads();
  }
#pragma unroll
  for (int r = 0; r < 8; ++r) {
    const int row = mt * 128 + ty + 16 * r;
#pragma unroll
    for (int c = 0; c < 8; ++c) {
      float v = acc[r][c];
      float sp = (v > 20.f) ? v : log1pf(__expf(v));   // stable softplus
      delta_out[row * 4096 + nt * 128 + tx + 16 * c] = sp;
    }
  }
}

// ---------------- scan pass 1: per-chunk P (cumprod dA) and H (zero-init state) ----------------
// grid (16, 32): x = d-tile of 256 channels, y = chunk. block 256 (1 thread = 1 channel).
__global__ __launch_bounds__(256) void scan1_kernel(const float* __restrict__ delta,
                                                    const float* __restrict__ x,
                                                    const float* __restrict__ A_log,
                                                    const float* __restrict__ dbc,
                                                    float* __restrict__ part) {
  __shared__ float Bs[CLEN][NS];
  const int t = threadIdx.x;
  const int d = blockIdx.x * 256 + t;
  const int g = blockIdx.y;
  const int l0 = g * CLEN;
#pragma unroll
  for (int i = 0; i < 8; ++i) {
    int f = t + i * 256;
    int l = f >> 4, n = f & 15;
    Bs[l][n] = dbc[(l0 + l) * NCOL + RNK + n];
  }
  __syncthreads();

  float al2[NS];
#pragma unroll
  for (int n = 0; n < NS; ++n) al2[n] = -expf(A_log[d * NS + n]) * 1.44269504f;
  bool uni = true;
#pragma unroll
  for (int n = 1; n < NS; ++n) uni = uni && (al2[n] == al2[0]);

  float h[NS], P[NS];
#pragma unroll
  for (int n = 0; n < NS; ++n) { h[n] = 0.f; P[n] = 1.f; }

  if (uni) {   // all 16 A values identical for this channel (true for this init) -> 1 exp/step
    const float a0 = al2[0];
    float Ps = 1.f;
    for (int l = 0; l < CLEN; ++l) {
      float dv = delta[(l0 + l) * 4096 + d];
      float xv = x[(l0 + l) * 4096 + d];
      float dx = dv * xv;
      float dA = fast_exp2(dv * a0);
      Ps *= dA;
      const float4* br = (const float4*)Bs[l];
      float4 b0 = br[0], b1 = br[1], b2 = br[2], b3 = br[3];
      h[0]  = fmaf(dA, h[0],  dx * b0.x); h[1]  = fmaf(dA, h[1],  dx * b0.y);
      h[2]  = fmaf(dA, h[2],  dx * b0.z); h[3]  = fmaf(dA, h[3],  dx * b0.w);
      h[4]  = fmaf(dA, h[4],  dx * b1.x); h[5]  = fmaf(dA, h[5],  dx * b1.y);
      h[6]  = fmaf(dA, h[6],  dx * b1.z); h[7]  = fmaf(dA, h[7],  dx * b1.w);
      h[8]  = fmaf(dA, h[8],  dx * b2.x); h[9]  = fmaf(dA, h[9],  dx * b2.y);
      h[10] = fmaf(dA, h[10], dx * b2.z); h[11] = fmaf(dA, h[11], dx * b2.w);
      h[12] = fmaf(dA, h[12], dx * b3.x); h[13] = fmaf(dA, h[13], dx * b3.y);
      h[14] = fmaf(dA, h[14], dx * b3.z); h[15] = fmaf(dA, h[15], dx * b3.w);
    }
#pragma unroll
    for (int n = 0; n < NS; ++n) P[n] = Ps;
  } else {     // generic path: 16 exps/step
    for (int l = 0; l < CLEN; ++l) {
      float dv = delta[(l0 + l) * 4096 + d];
      float xv = x[(l0 + l) * 4096 + d];
      float dx = dv * xv;
#pragma unroll
      for (int n = 0; n < NS; ++n) {
        float dA = fast_exp2(dv * al2[n]);
        h[n] = fmaf(dA, h[n], dx * Bs[l][n]);
        P[n] *= dA;
      }
    }
  }
  float* pg = part + (size_t)g * 32 * 4096;
#pragma unroll
  for (int n = 0; n < NS; ++n) {
    pg[n * 4096 + d] = P[n];
    pg[(NS + n) * 4096 + d] = h[n];
  }
}

// ---------------- scan pass 2: combine chunks; P-slot becomes h_in (state before chunk) ----------------
__global__ __launch_bounds__(256) void scan2_kernel(float* __restrict__ part) {
  const int idx = blockIdx.x * 256 + threadIdx.x;  // grid 256 -> 65536 = D*NS
  const int d = idx & 4095;
  const int n = idx >> 12;
  float h = 0.f;
  for (int g = 0; g < GCH; ++g) {
    float* pg = part + (size_t)g * 32 * 4096;
    float Pv = pg[n * 4096 + d];
    float Hv = pg[(NS + n) * 4096 + d];
    float nh = fmaf(Pv, h, Hv);
    pg[n * 4096 + d] = h;   // h_in for chunk g
    h = nh;
  }
}

// ---------------- scan pass 3: recompute local scan with h_in, produce output ----------------
// io aliases delta (read) and out (write) -- same element, read-before-write per thread.
__global__ __launch_bounds__(256) void scan3_kernel(float* io,
                                                    const float* __restrict__ x,
                                                    const float* __restrict__ A_log,
                                                    const float* __restrict__ dbc,
                                                    const float* __restrict__ Dvec,
                                                    const float* __restrict__ part) {
  __shared__ float Bs[CLEN][NS];
  __shared__ float Cs[CLEN][NS];
  const int t = threadIdx.x;
  const int d = blockIdx.x * 256 + t;
  const int g = blockIdx.y;
  const int l0 = g * CLEN;
#pragma unroll
  for (int i = 0; i < 8; ++i) {
    int f = t + i * 256;
    int l = f >> 4, n = f & 15;
    Bs[l][n] = dbc[(l0 + l) * NCOL + RNK + n];
    Cs[l][n] = dbc[(l0 + l) * NCOL + RNK + NS + n];
  }
  __syncthreads();

  float al2[NS];
#pragma unroll
  for (int n = 0; n < NS; ++n) al2[n] = -expf(A_log[d * NS + n]) * 1.44269504f;
  bool uni = true;
#pragma unroll
  for (int n = 1; n < NS; ++n) uni = uni && (al2[n] == al2[0]);

  float h[NS];
  const float* pg = part + (size_t)g * 32 * 4096;
#pragma unroll
  for (int n = 0; n < NS; ++n) h[n] = pg[n * 4096 + d];
  const float Dd = Dvec[d];

  if (uni) {
    const float a0 = al2[0];
    for (int l = 0; l < CLEN; ++l) {
      float dv = io[(size_t)(l0 + l) * 4096 + d];
      float xv = x[(l0 + l) * 4096 + d];
      float dx = dv * xv;
      float dA = fast_exp2(dv * a0);
      const float4* br = (const float4*)Bs[l];
      const float4* cr = (const float4*)Cs[l];
      float4 b0 = br[0], b1 = br[1], b2 = br[2], b3 = br[3];
      float4 c0 = cr[0], c1 = cr[1], c2 = cr[2], c3 = cr[3];
      float y = 0.f;
      h[0]  = fmaf(dA, h[0],  dx * b0.x); y = fmaf(h[0],  c0.x, y);
      h[1]  = fmaf(dA, h[1],  dx * b0.y); y = fmaf(h[1],  c0.y, y);
      h[2]  = fmaf(dA, h[2],  dx * b0.z); y = fmaf(h[2],  c0.z, y);
      h[3]  = fmaf(dA, h[3],  dx * b0.w); y = fmaf(h[3],  c0.w, y);
      h[4]  = fmaf(dA, h[4],  dx * b1.x); y = fmaf(h[4],  c1.x, y);
      h[5]  = fmaf(dA, h[5],  dx * b1.y); y = fmaf(h[5],  c1.y, y);
      h[6]  = fmaf(dA, h[6],  dx * b1.z); y = fmaf(h[6],  c1.z, y);
      h[7]  = fmaf(dA, h[7],  dx * b1.w); y = fmaf(h[7],  c1.w, y);
      h[8]  = fmaf(dA, h[8],  dx * b2.x); y = fmaf(h[8],  c2.x, y);
      h[9]  = fmaf(dA, h[9],  dx * b2.y); y = fmaf(h[9],  c2.y, y);
      h[10] = fmaf(dA, h[10], dx * b2.z); y = fmaf(h[10], c2.z, y);
      h[11] = fmaf(dA, h[11], dx * b2.w); y = fmaf(h[11], c2.w, y);
      h[12] = fmaf(dA, h[12], dx * b3.x); y = fmaf(h[12], c3.x, y);
      h[13] = fmaf(dA, h[13], dx * b3.y); y = fmaf(h[13], c3.y, y);
      h[14] = fmaf(dA, h[14], dx * b3.z); y = fmaf(h[14], c3.z, y);
      h[15] = fmaf(dA, h[15], dx * b3.w); y = fmaf(h[15], c3.w, y);
      io[(size_t)(l0 + l) * 4096 + d] = fmaf(xv, Dd, y);
    }
  } else {
    for (int l = 0; l < CLEN; ++l) {
      float dv = io[(size_t)(l0 + l) * 4096 + d];
      float xv = x[(l0 + l) * 4096 + d];
      float dx = dv * xv;
      float y = 0.f;
#pragma unroll
      for (int n = 0; n < NS; ++n) {
        float dA = fast_exp2(dv * al2[n]);
        h[n] = fmaf(dA, h[n], dx * Bs[l][n]);
        y = fmaf(h[n], Cs[l][n], y);
      }
      io[(size_t)(l0 + l) * 4096 + d] = fmaf(xv, Dd, y);
    }
  }
}

extern "C" void kernel_launch(void* const* d_in, const int* in_sizes, int n_in,
                              void* d_out, int out_size, void* d_ws, size_t ws_size,
                              hipStream_t stream) {
  const float* x    = (const float*)d_in[0];
  const float* Win  = (const float*)d_in[1];
  const float* Wd   = (const float*)d_in[2];
  const float* Alog = (const float*)d_in[3];
  const float* Dv   = (const float*)d_in[4];
  float* out = (float*)d_out;          // scratch for gemm1 partials, then delta, then output
  float* ws  = (float*)d_ws;           // 19.4 MB
  float* dbc  = ws;
  float* part = ws + PART_OFF;

  gemm1_kernel<<<1024, 256, 0, stream>>>(x, Win, out);          // partials -> d_out
  reduce_dbc_kernel<<<640, 256, 0, stream>>>(out, dbc);         // final dbc -> ws
  gemm2_kernel<<<1024, 256, 0, stream>>>(dbc, Wd, out);         // delta -> d_out
  scan1_kernel<<<dim3(16, 32), 256, 0, stream>>>(out, x, Alog, dbc, part);
  scan2_kernel<<<256, 256, 0, stream>>>(part);
  scan3_kernel<<<dim3(16, 32), 256, 0, stream>>>(out, x, Alog, dbc, Dv, part);
}

// Round 8
// 483.246 us; speedup vs baseline: 1.3938x; 1.3938x over previous
//
#include <hip/hip_runtime.h>
#include <math.h>
#include <stdint.h>

// Problem constants (fixed by the reference)
#define L_SEQ   4096
#define DI      4096   // d_inner
#define RNK     128    // dt_rank
#define NS      16     // d_state
#define NCOL    160    // dt_rank + 2*d_state
#define GCH     32     // scan chunks
#define CLEN    128    // L_SEQ / GCH
#define KSPLIT  16     // gemm1 K slices

// Buffers:
//   d_out (64 MB) triple-duty: gemm1 partials (16 x 2.6 MB) -> delta [L,D] -> output [L,D]
//   ws: [0, 655360) final dbc [L,160]; [655360, +4194304) chunk partials [G][32][D]
#define DBC_SLICE 655360
#define PART_OFF  655360

__device__ __forceinline__ float fast_exp2(float v) {
#if __has_builtin(__builtin_amdgcn_exp2f)
  return __builtin_amdgcn_exp2f(v);
#else
  return exp2f(v);
#endif
}

// async global->LDS, 16B per lane; LDS dest is wave-uniform base + lane*16 (HW).
typedef __attribute__((address_space(3))) char* lds_p_t;
typedef const __attribute__((address_space(1))) char* glb_p_t;
__device__ __forceinline__ void gll16(const float* g, float* l) {
  __builtin_amdgcn_global_load_lds((glb_p_t)(uintptr_t)(const void*)g,
                                   (lds_p_t)(uintptr_t)(void*)l, 16, 0, 0);
}

// ---------------- GEMM1: dbc[l,j] = sum_k x[l,k] * W_in[j,k] ----------------
// grid 1024: bx>>4 = m-tile (64 rows), bx&15 = K slice (256 K each, 8 chunks of 32).
// gll16 staging, XOR-swizzled (slot(row,q) holds global (row, q^(row&7))),
// linear LDS 28672 B -> 5 blocks/CU. VGPR capped at 128 via launch_bounds.
__device__ __forceinline__ void g1_stage(const float* __restrict__ x,
                                         const float* __restrict__ Win,
                                         float* xsb, float* wshb,
                                         int row0, int kb, int w, int l) {
#pragma unroll
  for (int i = 0; i < 2; ++i) {          // x tile: 64 rows x 32 k = 512 f4 = 8 calls
    const int j = 2 * w + i;
    const int idx = 64 * j + l;
    const int row = idx >> 3;            // 8 f4 per 32-float row
    const int q   = idx & 7;
    gll16(&x[(row0 + row) * 4096 + kb + ((q ^ (row & 7)) << 2)], &xsb[j * 256]);
  }
#pragma unroll
  for (int i = 0; i < 5; ++i) {          // W tile: 160 rows x 32 k = 1280 f4 = 20 calls
    const int j = 5 * w + i;
    const int idx = 64 * j + l;
    const int row = idx >> 3;            // 0..159
    const int q   = idx & 7;
    gll16(&Win[row * 4096 + kb + ((q ^ (row & 7)) << 2)], &wshb[j * 256]);
  }
}

__global__ __launch_bounds__(256, 4) void gemm1_kernel(const float* __restrict__ x,
                                                       const float* __restrict__ Win,
                                                       float* __restrict__ parts) {
  __shared__ float smem[7168];           // xsb [64][32] | wshb [160][32], 28672 B
  float* xsb  = smem;
  float* wshb = smem + 2048;
  const int t  = threadIdx.x;
  const int tx = t & 15, ty = t >> 4;
  const int w  = t >> 6, l = t & 63;
  const int mt = blockIdx.x >> 4;
  const int ks = blockIdx.x & 15;
  const int row0 = mt * 64;
  const int kbase0 = ks * 256;
  const int ua = 4 * (ty & 1);           // (4*ty + r)&7 = ua + r  (r<4)
  const int sb = tx & 7;                 // (tx + 16c)&7

  float acc[4][10];
#pragma unroll
  for (int r = 0; r < 4; ++r)
#pragma unroll
    for (int c = 0; c < 10; ++c) acc[r][c] = 0.f;

  for (int kc = 0; kc < 8; ++kc) {
    g1_stage(x, Win, xsb, wshb, row0, kbase0 + kc * 32, w, l);
    __syncthreads();                     // drains gll16 vmcnt
#pragma unroll
    for (int kk = 0; kk < 8; ++kk) {
      float4 xv[4];
#pragma unroll
      for (int r = 0; r < 4; ++r)
        xv[r] = *(const float4*)&xsb[(ty * 4 + r) * 32 + ((kk ^ (ua + r)) << 2)];
#pragma unroll
      for (int c = 0; c < 10; ++c) {
        float4 wv = *(const float4*)&wshb[(tx + 16 * c) * 32 + ((kk ^ sb) << 2)];
#pragma unroll
        for (int r = 0; r < 4; ++r) {
          acc[r][c] = fmaf(xv[r].x, wv.x, acc[r][c]);
          acc[r][c] = fmaf(xv[r].y, wv.y, acc[r][c]);
          acc[r][c] = fmaf(xv[r].z, wv.z, acc[r][c]);
          acc[r][c] = fmaf(xv[r].w, wv.w, acc[r][c]);
        }
      }
    }
    __syncthreads();
  }
  float* outp = parts + ks * DBC_SLICE;
#pragma unroll
  for (int r = 0; r < 4; ++r)
#pragma unroll
    for (int c = 0; c < 10; ++c)
      outp[(row0 + ty * 4 + r) * NCOL + tx + 16 * c] = acc[r][c];
}

// ---------------- reduce the 16 K-slices (in d_out scratch) into ws dbc ----------------
__global__ __launch_bounds__(256) void reduce_dbc_kernel(const float* __restrict__ parts,
                                                         float* __restrict__ dbc) {
  const int i = (blockIdx.x * 256 + threadIdx.x) * 4;  // grid 640 -> covers 655360
  float4 a = *(const float4*)&parts[i];
#pragma unroll
  for (int s = 1; s < KSPLIT; ++s) {
    float4 b = *(const float4*)&parts[(size_t)s * DBC_SLICE + i];
    a.x += b.x; a.y += b.y; a.z += b.z; a.w += b.w;
  }
  *(float4*)&dbc[i] = a;
}

// ---- GEMM2 + softplus: delta[l,d] = softplus(sum_k dbc[l,k]*W_delta[d,k]) ----
// grid 1024 (32x32 tiles of 128x128), block 256, thread 8x8.
// 2-phase double-buffer, K-chunk 16: stage(next) issued BEFORE compute(cur),
// ONE barrier per chunk. LDS 32768 B -> 5 blocks/CU. VGPR capped at 128.
// XOR swizzle: slot(row,q) holds global (row, q^(row&3)); read with kk^(row&3).
__device__ __forceinline__ void g2_stage(const float* __restrict__ dbc,
                                         const float* __restrict__ Wd,
                                         float* Ab, float* Bb, int kb,
                                         int mt, int nt, int w, int l) {
#pragma unroll
  for (int i = 0; i < 2; ++i) {          // A,B tiles: 128 rows x 16 k = 512 f4 = 8 calls each
    const int j = 2 * w + i;
    const int idx = 64 * j + l;
    const int row = idx >> 2;            // 4 f4 per 16-float row
    const int q   = idx & 3;
    const int sq  = (q ^ (row & 3)) << 2;
    gll16(&dbc[(mt * 128 + row) * NCOL + kb + sq], &Ab[j * 256]);
    gll16(&Wd [(nt * 128 + row) * RNK  + kb + sq], &Bb[j * 256]);
  }
}

__global__ __launch_bounds__(256, 4) void gemm2_kernel(const float* __restrict__ dbc,
                                                       const float* __restrict__ Wd,
                                                       float* __restrict__ delta_out) {
  __shared__ float smem[8192];           // 2 bufs x (Ab 2048 | Bb 2048), 32768 B
  const int t  = threadIdx.x;
  const int tx = t & 15, ty = t >> 4;
  const int w  = t >> 6, l = t & 63;
  const int mt = blockIdx.x & 31, nt = blockIdx.x >> 5;
  const int sa = ty & 3;                 // (ty+16r)&3
  const int sb = tx & 3;                 // (tx+16c)&3

  float acc[8][8];
#pragma unroll
  for (int r = 0; r < 8; ++r)
#pragma unroll
    for (int c = 0; c < 8; ++c) acc[r][c] = 0.f;

  g2_stage(dbc, Wd, smem, smem + 2048, 0, mt, nt, w, l);
  __syncthreads();

  for (int kc = 0; kc < 8; ++kc) {
    if (kc < 7) {
      float* nb = smem + ((kc + 1) & 1) * 4096;
      g2_stage(dbc, Wd, nb, nb + 2048, (kc + 1) * 16, mt, nt, w, l);
    }
    const float* Ab = smem + (kc & 1) * 4096;
    const float* Bb = Ab + 2048;
#pragma unroll
    for (int kk = 0; kk < 4; ++kk) {
      float4 av[8];
#pragma unroll
      for (int r = 0; r < 8; ++r)
        av[r] = *(const float4*)&Ab[(ty + 16 * r) * 16 + ((kk ^ sa) << 2)];
#pragma unroll
      for (int c = 0; c < 8; ++c) {
        float4 bv = *(const float4*)&Bb[(tx + 16 * c) * 16 + ((kk ^ sb) << 2)];
#pragma unroll
        for (int r = 0; r < 8; ++r) {
          acc[r][c] = fmaf(av[r].x, bv.x, acc[r][c]);
          acc[r][c] = fmaf(av[r].y, bv.y, acc[r][c]);
          acc[r][c] = fmaf(av[r].z, bv.z, acc[r][c]);
          acc[r][c] = fmaf(av[r].w, bv.w, acc[r][c]);
        }
      }
    }
    __syncthreads();                     // drains prefetch vmcnt + read/write hazard
  }
#pragma unroll
  for (int r = 0; r < 8; ++r) {
    const int row = mt * 128 + ty + 16 * r;
#pragma unroll
    for (int c = 0; c < 8; ++c) {
      float v = acc[r][c];
      float sp = (v > 20.f) ? v : log1pf(__expf(v));   // stable softplus
      delta_out[row * 4096 + nt * 128 + tx + 16 * c] = sp;
    }
  }
}

// ---------------- scan pass 1: per-chunk P (cumprod dA) and H (zero-init state) ----------------
// grid (16, 32): x = d-tile of 256 channels, y = chunk. block 256 (1 thread = 1 channel).
__global__ __launch_bounds__(256) void scan1_kernel(const float* __restrict__ delta,
                                                    const float* __restrict__ x,
                                                    const float* __restrict__ A_log,
                                                    const float* __restrict__ dbc,
                                                    float* __restrict__ part) {
  __shared__ float Bs[CLEN][NS];
  const int t = threadIdx.x;
  const int d = blockIdx.x * 256 + t;
  const int g = blockIdx.y;
  const int l0 = g * CLEN;
#pragma unroll
  for (int i = 0; i < 8; ++i) {
    int f = t + i * 256;
    int l = f >> 4, n = f & 15;
    Bs[l][n] = dbc[(l0 + l) * NCOL + RNK + n];
  }
  __syncthreads();

  float al2[NS];
#pragma unroll
  for (int n = 0; n < NS; ++n) al2[n] = -expf(A_log[d * NS + n]) * 1.44269504f;
  bool uni = true;
#pragma unroll
  for (int n = 1; n < NS; ++n) uni = uni && (al2[n] == al2[0]);

  float h[NS], P[NS];
#pragma unroll
  for (int n = 0; n < NS; ++n) { h[n] = 0.f; P[n] = 1.f; }

  if (uni) {   // all 16 A values identical for this channel (true for this init) -> 1 exp/step
    const float a0 = al2[0];
    float Ps = 1.f;
    for (int l = 0; l < CLEN; ++l) {
      float dv = delta[(l0 + l) * 4096 + d];
      float xv = x[(l0 + l) * 4096 + d];
      float dx = dv * xv;
      float dA = fast_exp2(dv * a0);
      Ps *= dA;
      const float4* br = (const float4*)Bs[l];
      float4 b0 = br[0], b1 = br[1], b2 = br[2], b3 = br[3];
      h[0]  = fmaf(dA, h[0],  dx * b0.x); h[1]  = fmaf(dA, h[1],  dx * b0.y);
      h[2]  = fmaf(dA, h[2],  dx * b0.z); h[3]  = fmaf(dA, h[3],  dx * b0.w);
      h[4]  = fmaf(dA, h[4],  dx * b1.x); h[5]  = fmaf(dA, h[5],  dx * b1.y);
      h[6]  = fmaf(dA, h[6],  dx * b1.z); h[7]  = fmaf(dA, h[7],  dx * b1.w);
      h[8]  = fmaf(dA, h[8],  dx * b2.x); h[9]  = fmaf(dA, h[9],  dx * b2.y);
      h[10] = fmaf(dA, h[10], dx * b2.z); h[11] = fmaf(dA, h[11], dx * b2.w);
      h[12] = fmaf(dA, h[12], dx * b3.x); h[13] = fmaf(dA, h[13], dx * b3.y);
      h[14] = fmaf(dA, h[14], dx * b3.z); h[15] = fmaf(dA, h[15], dx * b3.w);
    }
#pragma unroll
    for (int n = 0; n < NS; ++n) P[n] = Ps;
  } else {     // generic path: 16 exps/step
    for (int l = 0; l < CLEN; ++l) {
      float dv = delta[(l0 + l) * 4096 + d];
      float xv = x[(l0 + l) * 4096 + d];
      float dx = dv * xv;
#pragma unroll
      for (int n = 0; n < NS; ++n) {
        float dA = fast_exp2(dv * al2[n]);
        h[n] = fmaf(dA, h[n], dx * Bs[l][n]);
        P[n] *= dA;
      }
    }
  }
  float* pg = part + (size_t)g * 32 * 4096;
#pragma unroll
  for (int n = 0; n < NS; ++n) {
    pg[n * 4096 + d] = P[n];
    pg[(NS + n) * 4096 + d] = h[n];
  }
}

// ---------------- scan pass 2: combine chunks; P-slot becomes h_in (state before chunk) ----------------
__global__ __launch_bounds__(256) void scan2_kernel(float* __restrict__ part) {
  const int idx = blockIdx.x * 256 + threadIdx.x;  // grid 256 -> 65536 = D*NS
  const int d = idx & 4095;
  const int n = idx >> 12;
  float h = 0.f;
  for (int g = 0; g < GCH; ++g) {
    float* pg = part + (size_t)g * 32 * 4096;
    float Pv = pg[n * 4096 + d];
    float Hv = pg[(NS + n) * 4096 + d];
    float nh = fmaf(Pv, h, Hv);
    pg[n * 4096 + d] = h;   // h_in for chunk g
    h = nh;
  }
}

// ---------------- scan pass 3: recompute local scan with h_in, produce output ----------------
// io aliases delta (read) and out (write) -- same element, read-before-write per thread.
__global__ __launch_bounds__(256) void scan3_kernel(float* io,
                                                    const float* __restrict__ x,
                                                    const float* __restrict__ A_log,
                                                    const float* __restrict__ dbc,
                                                    const float* __restrict__ Dvec,
                                                    const float* __restrict__ part) {
  __shared__ float Bs[CLEN][NS];
  __shared__ float Cs[CLEN][NS];
  const int t = threadIdx.x;
  const int d = blockIdx.x * 256 + t;
  const int g = blockIdx.y;
  const int l0 = g * CLEN;
#pragma unroll
  for (int i = 0; i < 8; ++i) {
    int f = t + i * 256;
    int l = f >> 4, n = f & 15;
    Bs[l][n] = dbc[(l0 + l) * NCOL + RNK + n];
    Cs[l][n] = dbc[(l0 + l) * NCOL + RNK + NS + n];
  }
  __syncthreads();

  float al2[NS];
#pragma unroll
  for (int n = 0; n < NS; ++n) al2[n] = -expf(A_log[d * NS + n]) * 1.44269504f;
  bool uni = true;
#pragma unroll
  for (int n = 1; n < NS; ++n) uni = uni && (al2[n] == al2[0]);

  float h[NS];
  const float* pg = part + (size_t)g * 32 * 4096;
#pragma unroll
  for (int n = 0; n < NS; ++n) h[n] = pg[n * 4096 + d];
  const float Dd = Dvec[d];

  if (uni) {
    const float a0 = al2[0];
    for (int l = 0; l < CLEN; ++l) {
      float dv = io[(size_t)(l0 + l) * 4096 + d];
      float xv = x[(l0 + l) * 4096 + d];
      float dx = dv * xv;
      float dA = fast_exp2(dv * a0);
      const float4* br = (const float4*)Bs[l];
      const float4* cr = (const float4*)Cs[l];
      float4 b0 = br[0], b1 = br[1], b2 = br[2], b3 = br[3];
      float4 c0 = cr[0], c1 = cr[1], c2 = cr[2], c3 = cr[3];
      float y = 0.f;
      h[0]  = fmaf(dA, h[0],  dx * b0.x); y = fmaf(h[0],  c0.x, y);
      h[1]  = fmaf(dA, h[1],  dx * b0.y); y = fmaf(h[1],  c0.y, y);
      h[2]  = fmaf(dA, h[2],  dx * b0.z); y = fmaf(h[2],  c0.z, y);
      h[3]  = fmaf(dA, h[3],  dx * b0.w); y = fmaf(h[3],  c0.w, y);
      h[4]  = fmaf(dA, h[4],  dx * b1.x); y = fmaf(h[4],  c1.x, y);
      h[5]  = fmaf(dA, h[5],  dx * b1.y); y = fmaf(h[5],  c1.y, y);
      h[6]  = fmaf(dA, h[6],  dx * b1.z); y = fmaf(h[6],  c1.z, y);
      h[7]  = fmaf(dA, h[7],  dx * b1.w); y = fmaf(h[7],  c1.w, y);
      h[8]  = fmaf(dA, h[8],  dx * b2.x); y = fmaf(h[8],  c2.x, y);
      h[9]  = fmaf(dA, h[9],  dx * b2.y); y = fmaf(h[9],  c2.y, y);
      h[10] = fmaf(dA, h[10], dx * b2.z); y = fmaf(h[10], c2.z, y);
      h[11] = fmaf(dA, h[11], dx * b2.w); y = fmaf(h[11], c2.w, y);
      h[12] = fmaf(dA, h[12], dx * b3.x); y = fmaf(h[12], c3.x, y);
      h[13] = fmaf(dA, h[13], dx * b3.y); y = fmaf(h[13], c3.y, y);
      h[14] = fmaf(dA, h[14], dx * b3.z); y = fmaf(h[14], c3.z, y);
      h[15] = fmaf(dA, h[15], dx * b3.w); y = fmaf(h[15], c3.w, y);
      io[(size_t)(l0 + l) * 4096 + d] = fmaf(xv, Dd, y);
    }
  } else {
    for (int l = 0; l < CLEN; ++l) {
      float dv = io[(size_t)(l0 + l) * 4096 + d];
      float xv = x[(l0 + l) * 4096 + d];
      float dx = dv * xv;
      float y = 0.f;
#pragma unroll
      for (int n = 0; n < NS; ++n) {
        float dA = fast_exp2(dv * al2[n]);
        h[n] = fmaf(dA, h[n], dx * Bs[l][n]);
        y = fmaf(h[n], Cs[l][n], y);
      }
      io[(size_t)(l0 + l) * 4096 + d] = fmaf(xv, Dd, y);
    }
  }
}

extern "C" void kernel_launch(void* const* d_in, const int* in_sizes, int n_in,
                              void* d_out, int out_size, void* d_ws, size_t ws_size,
                              hipStream_t stream) {
  const float* x    = (const float*)d_in[0];
  const float* Win  = (const float*)d_in[1];
  const float* Wd   = (const float*)d_in[2];
  const float* Alog = (const float*)d_in[3];
  const float* Dv   = (const float*)d_in[4];
  float* out = (float*)d_out;          // scratch for gemm1 partials, then delta, then output
  float* ws  = (float*)d_ws;           // 19.4 MB
  float* dbc  = ws;
  float* part = ws + PART_OFF;

  gemm1_kernel<<<1024, 256, 0, stream>>>(x, Win, out);          // partials -> d_out
  reduce_dbc_kernel<<<640, 256, 0, stream>>>(out, dbc);         // final dbc -> ws
  gemm2_kernel<<<1024, 256, 0, stream>>>(dbc, Wd, out);         // delta -> d_out
  scan1_kernel<<<dim3(16, 32), 256, 0, stream>>>(out, x, Alog, dbc, part);
  scan2_kernel<<<256, 256, 0, stream>>>(part);
  scan3_kernel<<<dim3(16, 32), 256, 0, stream>>>(out, x, Alog, dbc, Dv, part);
}

// Round 10
// 375.363 us; speedup vs baseline: 1.7944x; 1.2874x over previous
//
#include <hip/hip_runtime.h>
#include <math.h>
#include <stdint.h>

// Problem constants (fixed by the reference)
#define L_SEQ   4096
#define DI      4096   // d_inner
#define RNK     128    // dt_rank
#define NS      16     // d_state
#define NCOL    160    // dt_rank + 2*d_state
#define GCH     32     // scan chunks
#define CLEN    128    // L_SEQ / GCH
#define KSPLIT  16     // gemm1 K slices

// Buffers:
//   d_out (64 MB): gemm1 partials (16 x 2.6 MB) -> delta [L,D] -> output [L,D]
//   ws (23.4 MB): [0,655360) dbc fp32 (only B/C cols 128..159 are consumed);
//                 [655360, 4849664) chunk partials [G][32][D];
//                 then 4 x 1MB bf16: dbch, dbcl, Wdh, Wdl
#define DBC_SLICE 655360
#define PART_OFF  655360
#define BF_OFF    4849664   // float offset where the ushort arrays start
#define DSZ       524288    // 4096*128 elements

typedef __attribute__((ext_vector_type(8))) short bf16x8;   // 8 bf16 = 4 VGPRs
typedef __attribute__((ext_vector_type(4))) float f32x4;

__device__ __forceinline__ float fast_exp2(float v) {
#if __has_builtin(__builtin_amdgcn_exp2f)
  return __builtin_amdgcn_exp2f(v);
#else
  return exp2f(v);
#endif
}

__device__ __forceinline__ unsigned short f2bf(float f) {     // RNE bf16 truncation
  uint32_t u = __float_as_uint(f);
  uint32_t r = (u + 0x7FFFu + ((u >> 16) & 1u)) >> 16;
  return (unsigned short)r;
}
__device__ __forceinline__ float bf2f(unsigned short b) {
  return __uint_as_float(((uint32_t)b) << 16);
}

// ---------------- GEMM1 (R6 known-good): dbc[l,j] = sum_k x[l,k]*W_in[j,k] ----------------
// grid 1024: bx>>4 = m-tile (64 rows), bx&15 = K slice (256 K each, 8 chunks of 32).
__global__ __launch_bounds__(256) void gemm1_kernel(const float* __restrict__ x,
                                                    const float* __restrict__ Win,
                                                    float* __restrict__ parts) {
  __shared__ float xs[64][36];
  __shared__ float wsh[160][36];
  const int t  = threadIdx.x;
  const int tx = t & 15, ty = t >> 4;
  const int mt = blockIdx.x >> 4;
  const int ks = blockIdx.x & 15;
  const int row0 = mt * 64;
  const int kbase0 = ks * 256;

  float acc[4][10];
#pragma unroll
  for (int r = 0; r < 4; ++r)
#pragma unroll
    for (int c = 0; c < 10; ++c) acc[r][c] = 0.f;

  for (int kc = 0; kc < 8; ++kc) {
    const int kb = kbase0 + kc * 32;
#pragma unroll
    for (int i = 0; i < 2; ++i) {
      int f = t + i * 256;
      int r = f >> 3, c4 = (f & 7) * 4;
      *(float4*)&xs[r][c4] = *(const float4*)&x[(row0 + r) * 4096 + kb + c4];
    }
#pragma unroll
    for (int i = 0; i < 5; ++i) {
      int f = t + i * 256;
      int r = f >> 3, c4 = (f & 7) * 4;
      *(float4*)&wsh[r][c4] = *(const float4*)&Win[r * 4096 + kb + c4];
    }
    __syncthreads();
#pragma unroll
    for (int kk = 0; kk < 8; ++kk) {
      float4 xv[4];
#pragma unroll
      for (int r = 0; r < 4; ++r) xv[r] = *(float4*)&xs[ty * 4 + r][kk * 4];
#pragma unroll
      for (int c = 0; c < 10; ++c) {
        float4 wv = *(float4*)&wsh[tx + 16 * c][kk * 4];
#pragma unroll
        for (int r = 0; r < 4; ++r) {
          acc[r][c] = fmaf(xv[r].x, wv.x, acc[r][c]);
          acc[r][c] = fmaf(xv[r].y, wv.y, acc[r][c]);
          acc[r][c] = fmaf(xv[r].z, wv.z, acc[r][c]);
          acc[r][c] = fmaf(xv[r].w, wv.w, acc[r][c]);
        }
      }
    }
    __syncthreads();
  }
  float* outp = parts + ks * DBC_SLICE;
#pragma unroll
  for (int r = 0; r < 4; ++r)
#pragma unroll
    for (int c = 0; c < 10; ++c)
      outp[(row0 + ty * 4 + r) * NCOL + tx + 16 * c] = acc[r][c];
}

// ------- reduce 16 K-slices; delta cols -> bf16 hi/lo split, B/C cols -> fp32 dbc -------
__global__ __launch_bounds__(256) void reduce_dbc_kernel(const float* __restrict__ parts,
                                                         float* __restrict__ dbc,
                                                         unsigned short* __restrict__ dbch,
                                                         unsigned short* __restrict__ dbcl) {
  const int i = (blockIdx.x * 256 + threadIdx.x) * 4;  // grid 640 -> 655360
  float4 a = *(const float4*)&parts[i];
#pragma unroll
  for (int s = 1; s < KSPLIT; ++s) {
    float4 b = *(const float4*)&parts[(size_t)s * DBC_SLICE + i];
    a.x += b.x; a.y += b.y; a.z += b.z; a.w += b.w;
  }
  const int row = i / NCOL;
  const int col = i - row * NCOL;      // multiple of 4; quad never crosses a row
  if (col < RNK) {                     // delta part -> bf16 split only
    float v[4] = {a.x, a.y, a.z, a.w};
    ushort4 h, lo;
    unsigned short* hp = (unsigned short*)&h;
    unsigned short* lp = (unsigned short*)&lo;
#pragma unroll
    for (int q = 0; q < 4; ++q) {
      hp[q] = f2bf(v[q]);
      lp[q] = f2bf(v[q] - bf2f(hp[q]));
    }
    *(ushort4*)&dbch[row * RNK + col] = h;
    *(ushort4*)&dbcl[row * RNK + col] = lo;
  } else {                             // B/C part -> fp32 (consumed by scans)
    *(float4*)&dbc[i] = a;
  }
}

// ---------------- split W_delta into bf16 hi/lo ----------------
__global__ __launch_bounds__(256) void split_wd_kernel(const float* __restrict__ Wd,
                                                       unsigned short* __restrict__ Wdh,
                                                       unsigned short* __restrict__ Wdl) {
  const int i = (blockIdx.x * 256 + threadIdx.x) * 4;  // grid 512 -> 524288
  float4 a = *(const float4*)&Wd[i];
  float v[4] = {a.x, a.y, a.z, a.w};
  ushort4 h, lo;
  unsigned short* hp = (unsigned short*)&h;
  unsigned short* lp = (unsigned short*)&lo;
#pragma unroll
  for (int q = 0; q < 4; ++q) {
    hp[q] = f2bf(v[q]);
    lp[q] = f2bf(v[q] - bf2f(hp[q]));
  }
  *(ushort4*)&Wdh[i] = h;
  *(ushort4*)&Wdl[i] = lo;
}

// ---- GEMM2 via bf16x3 MFMA: delta[l,d] = softplus(sum_k dbc[l,k]*Wd[d,k]) ----
// a = ah+al, b = bh+bl (bf16 splits); a*b ~= ah*bh + ah*bl + al*bh, fp32 MFMA accum.
// No LDS: fragments read directly from global (operands are 4MB total, L2-resident).
// grid 2048 = 64 mt x 32 nt; block 256 = 4 waves (2 wr x 2 wc);
// wave tile 32(m) x 64(n) = 2 x 4 tiles of 16x16; K = 4 steps of 32.
// A-frag: lane l -> row=l&15, k=(l>>4)*8+j (8 consecutive bf16 = dwordx4).
// C/D:    lane l, reg r -> row=(l>>4)*4+r, col=l&15  [verified m89 mapping].
__global__ __launch_bounds__(256) void gemm2_kernel(const unsigned short* __restrict__ dbch,
                                                    const unsigned short* __restrict__ dbcl,
                                                    const unsigned short* __restrict__ Wdh,
                                                    const unsigned short* __restrict__ Wdl,
                                                    float* __restrict__ delta_out) {
  const int t  = threadIdx.x;
  const int w  = t >> 6, l = t & 63;
  const int lr = l & 15;               // A-row / B-col / D-col
  const int lk = l >> 4;               // k-group 0..3
  const int mt = blockIdx.x & 63, nt = blockIdx.x >> 6;
  const int wr = w >> 1, wc = w & 1;
  const int m0 = mt * 64 + wr * 32;
  const int n0 = nt * 128 + wc * 64;

  f32x4 acc[2][4];
#pragma unroll
  for (int i = 0; i < 2; ++i)
#pragma unroll
    for (int j = 0; j < 4; ++j)
      acc[i][j] = (f32x4){0.f, 0.f, 0.f, 0.f};

#pragma unroll
  for (int ks = 0; ks < 4; ++ks) {
    const int k0 = ks * 32 + lk * 8;
    bf16x8 ah[2], al_[2], bh[4], bl[4];
#pragma unroll
    for (int i = 0; i < 2; ++i) {
      ah[i]  = *(const bf16x8*)&dbch[(m0 + i * 16 + lr) * RNK + k0];
      al_[i] = *(const bf16x8*)&dbcl[(m0 + i * 16 + lr) * RNK + k0];
    }
#pragma unroll
    for (int j = 0; j < 4; ++j) {
      bh[j] = *(const bf16x8*)&Wdh[(n0 + j * 16 + lr) * RNK + k0];
      bl[j] = *(const bf16x8*)&Wdl[(n0 + j * 16 + lr) * RNK + k0];
    }
#pragma unroll
    for (int i = 0; i < 2; ++i)
#pragma unroll
      for (int j = 0; j < 4; ++j) {
        acc[i][j] = __builtin_amdgcn_mfma_f32_16x16x32_bf16(ah[i],  bh[j], acc[i][j], 0, 0, 0);
        acc[i][j] = __builtin_amdgcn_mfma_f32_16x16x32_bf16(ah[i],  bl[j], acc[i][j], 0, 0, 0);
        acc[i][j] = __builtin_amdgcn_mfma_f32_16x16x32_bf16(al_[i], bh[j], acc[i][j], 0, 0, 0);
      }
  }

#pragma unroll
  for (int i = 0; i < 2; ++i)
#pragma unroll
    for (int j = 0; j < 4; ++j)
#pragma unroll
      for (int r = 0; r < 4; ++r) {
        const int row = m0 + i * 16 + lk * 4 + r;
        const int col = n0 + j * 16 + lr;
        float v = acc[i][j][r];
        float sp = (v > 20.f) ? v : log1pf(__expf(v));   // stable softplus
        delta_out[row * 4096 + col] = sp;
      }
}

// ---------------- scan pass 1 (unchanged) ----------------
__global__ __launch_bounds__(256) void scan1_kernel(const float* __restrict__ delta,
                                                    const float* __restrict__ x,
                                                    const float* __restrict__ A_log,
                                                    const float* __restrict__ dbc,
                                                    float* __restrict__ part) {
  __shared__ float Bs[CLEN][NS];
  const int t = threadIdx.x;
  const int d = blockIdx.x * 256 + t;
  const int g = blockIdx.y;
  const int l0 = g * CLEN;
#pragma unroll
  for (int i = 0; i < 8; ++i) {
    int f = t + i * 256;
    int l = f >> 4, n = f & 15;
    Bs[l][n] = dbc[(l0 + l) * NCOL + RNK + n];
  }
  __syncthreads();

  float al2[NS];
#pragma unroll
  for (int n = 0; n < NS; ++n) al2[n] = -expf(A_log[d * NS + n]) * 1.44269504f;
  bool uni = true;
#pragma unroll
  for (int n = 1; n < NS; ++n) uni = uni && (al2[n] == al2[0]);

  float h[NS], P[NS];
#pragma unroll
  for (int n = 0; n < NS; ++n) { h[n] = 0.f; P[n] = 1.f; }

  if (uni) {
    const float a0 = al2[0];
    float Ps = 1.f;
    for (int l = 0; l < CLEN; ++l) {
      float dv = delta[(l0 + l) * 4096 + d];
      float xv = x[(l0 + l) * 4096 + d];
      float dx = dv * xv;
      float dA = fast_exp2(dv * a0);
      Ps *= dA;
      const float4* br = (const float4*)Bs[l];
      float4 b0 = br[0], b1 = br[1], b2 = br[2], b3 = br[3];
      h[0]  = fmaf(dA, h[0],  dx * b0.x); h[1]  = fmaf(dA, h[1],  dx * b0.y);
      h[2]  = fmaf(dA, h[2],  dx * b0.z); h[3]  = fmaf(dA, h[3],  dx * b0.w);
      h[4]  = fmaf(dA, h[4],  dx * b1.x); h[5]  = fmaf(dA, h[5],  dx * b1.y);
      h[6]  = fmaf(dA, h[6],  dx * b1.z); h[7]  = fmaf(dA, h[7],  dx * b1.w);
      h[8]  = fmaf(dA, h[8],  dx * b2.x); h[9]  = fmaf(dA, h[9],  dx * b2.y);
      h[10] = fmaf(dA, h[10], dx * b2.z); h[11] = fmaf(dA, h[11], dx * b2.w);
      h[12] = fmaf(dA, h[12], dx * b3.x); h[13] = fmaf(dA, h[13], dx * b3.y);
      h[14] = fmaf(dA, h[14], dx * b3.z); h[15] = fmaf(dA, h[15], dx * b3.w);
    }
#pragma unroll
    for (int n = 0; n < NS; ++n) P[n] = Ps;
  } else {
    for (int l = 0; l < CLEN; ++l) {
      float dv = delta[(l0 + l) * 4096 + d];
      float xv = x[(l0 + l) * 4096 + d];
      float dx = dv * xv;
#pragma unroll
      for (int n = 0; n < NS; ++n) {
        float dA = fast_exp2(dv * al2[n]);
        h[n] = fmaf(dA, h[n], dx * Bs[l][n]);
        P[n] *= dA;
      }
    }
  }
  float* pg = part + (size_t)g * 32 * 4096;
#pragma unroll
  for (int n = 0; n < NS; ++n) {
    pg[n * 4096 + d] = P[n];
    pg[(NS + n) * 4096 + d] = h[n];
  }
}

// ---------------- scan pass 2 (unchanged) ----------------
__global__ __launch_bounds__(256) void scan2_kernel(float* __restrict__ part) {
  const int idx = blockIdx.x * 256 + threadIdx.x;
  const int d = idx & 4095;
  const int n = idx >> 12;
  float h = 0.f;
  for (int g = 0; g < GCH; ++g) {
    float* pg = part + (size_t)g * 32 * 4096;
    float Pv = pg[n * 4096 + d];
    float Hv = pg[(NS + n) * 4096 + d];
    float nh = fmaf(Pv, h, Hv);
    pg[n * 4096 + d] = h;
    h = nh;
  }
}

// ---------------- scan pass 3 (unchanged) ----------------
__global__ __launch_bounds__(256) void scan3_kernel(float* io,
                                                    const float* __restrict__ x,
                                                    const float* __restrict__ A_log,
                                                    const float* __restrict__ dbc,
                                                    const float* __restrict__ Dvec,
                                                    const float* __restrict__ part) {
  __shared__ float Bs[CLEN][NS];
  __shared__ float Cs[CLEN][NS];
  const int t = threadIdx.x;
  const int d = blockIdx.x * 256 + t;
  const int g = blockIdx.y;
  const int l0 = g * CLEN;
#pragma unroll
  for (int i = 0; i < 8; ++i) {
    int f = t + i * 256;
    int l = f >> 4, n = f & 15;
    Bs[l][n] = dbc[(l0 + l) * NCOL + RNK + n];
    Cs[l][n] = dbc[(l0 + l) * NCOL + RNK + NS + n];
  }
  __syncthreads();

  float al2[NS];
#pragma unroll
  for (int n = 0; n < NS; ++n) al2[n] = -expf(A_log[d * NS + n]) * 1.44269504f;
  bool uni = true;
#pragma unroll
  for (int n = 1; n < NS; ++n) uni = uni && (al2[n] == al2[0]);

  float h[NS];
  const float* pg = part + (size_t)g * 32 * 4096;
#pragma unroll
  for (int n = 0; n < NS; ++n) h[n] = pg[n * 4096 + d];
  const float Dd = Dvec[d];

  if (uni) {
    const float a0 = al2[0];
    for (int l = 0; l < CLEN; ++l) {
      float dv = io[(size_t)(l0 + l) * 4096 + d];
      float xv = x[(l0 + l) * 4096 + d];
      float dx = dv * xv;
      float dA = fast_exp2(dv * a0);
      const float4* br = (const float4*)Bs[l];
      const float4* cr = (const float4*)Cs[l];
      float4 b0 = br[0], b1 = br[1], b2 = br[2], b3 = br[3];
      float4 c0 = cr[0], c1 = cr[1], c2 = cr[2], c3 = cr[3];
      float y = 0.f;
      h[0]  = fmaf(dA, h[0],  dx * b0.x); y = fmaf(h[0],  c0.x, y);
      h[1]  = fmaf(dA, h[1],  dx * b0.y); y = fmaf(h[1],  c0.y, y);
      h[2]  = fmaf(dA, h[2],  dx * b0.z); y = fmaf(h[2],  c0.z, y);
      h[3]  = fmaf(dA, h[3],  dx * b0.w); y = fmaf(h[3],  c0.w, y);
      h[4]  = fmaf(dA, h[4],  dx * b1.x); y = fmaf(h[4],  c1.x, y);
      h[5]  = fmaf(dA, h[5],  dx * b1.y); y = fmaf(h[5],  c1.y, y);
      h[6]  = fmaf(dA, h[6],  dx * b1.z); y = fmaf(h[6],  c1.z, y);
      h[7]  = fmaf(dA, h[7],  dx * b1.w); y = fmaf(h[7],  c1.w, y);
      h[8]  = fmaf(dA, h[8],  dx * b2.x); y = fmaf(h[8],  c2.x, y);
      h[9]  = fmaf(dA, h[9],  dx * b2.y); y = fmaf(h[9],  c2.y, y);
      h[10] = fmaf(dA, h[10], dx * b2.z); y = fmaf(h[10], c2.z, y);
      h[11] = fmaf(dA, h[11], dx * b2.w); y = fmaf(h[11], c2.w, y);
      h[12] = fmaf(dA, h[12], dx * b3.x); y = fmaf(h[12], c3.x, y);
      h[13] = fmaf(dA, h[13], dx * b3.y); y = fmaf(h[13], c3.y, y);
      h[14] = fmaf(dA, h[14], dx * b3.z); y = fmaf(h[14], c3.z, y);
      h[15] = fmaf(dA, h[15], dx * b3.w); y = fmaf(h[15], c3.w, y);
      io[(size_t)(l0 + l) * 4096 + d] = fmaf(xv, Dd, y);
    }
  } else {
    for (int l = 0; l < CLEN; ++l) {
      float dv = io[(size_t)(l0 + l) * 4096 + d];
      float xv = x[(l0 + l) * 4096 + d];
      float dx = dv * xv;
      float y = 0.f;
#pragma unroll
      for (int n = 0; n < NS; ++n) {
        float dA = fast_exp2(dv * al2[n]);
        h[n] = fmaf(dA, h[n], dx * Bs[l][n]);
        y = fmaf(h[n], Cs[l][n], y);
      }
      io[(size_t)(l0 + l) * 4096 + d] = fmaf(xv, Dd, y);
    }
  }
}

extern "C" void kernel_launch(void* const* d_in, const int* in_sizes, int n_in,
                              void* d_out, int out_size, void* d_ws, size_t ws_size,
                              hipStream_t stream) {
  const float* x    = (const float*)d_in[0];
  const float* Win  = (const float*)d_in[1];
  const float* Wd   = (const float*)d_in[2];
  const float* Alog = (const float*)d_in[3];
  const float* Dv   = (const float*)d_in[4];
  float* out = (float*)d_out;          // gemm1 partials -> delta -> output
  float* ws  = (float*)d_ws;           // 23.4 MB
  float* dbc  = ws;
  float* part = ws + PART_OFF;
  unsigned short* dbch = (unsigned short*)(ws + BF_OFF);
  unsigned short* dbcl = dbch + DSZ;
  unsigned short* wdh  = dbcl + DSZ;
  unsigned short* wdl  = wdh + DSZ;

  gemm1_kernel<<<1024, 256, 0, stream>>>(x, Win, out);             // partials -> d_out
  reduce_dbc_kernel<<<640, 256, 0, stream>>>(out, dbc, dbch, dbcl);
  split_wd_kernel<<<512, 256, 0, stream>>>(Wd, wdh, wdl);
  gemm2_kernel<<<2048, 256, 0, stream>>>(dbch, dbcl, wdh, wdl, out);  // delta -> d_out
  scan1_kernel<<<dim3(16, 32), 256, 0, stream>>>(out, x, Alog, dbc, part);
  scan2_kernel<<<256, 256, 0, stream>>>(part);
  scan3_kernel<<<dim3(16, 32), 256, 0, stream>>>(out, x, Alog, dbc, Dv, part);
}

// Round 11
// 373.828 us; speedup vs baseline: 1.8018x; 1.0041x over previous
//
#include <hip/hip_runtime.h>
#include <math.h>
#include <stdint.h>

// Problem constants (fixed by the reference)
#define L_SEQ   4096
#define DI      4096   // d_inner
#define RNK     128    // dt_rank
#define NS      16     // d_state
#define NCOL    160    // dt_rank + 2*d_state
#define GCH     32     // scan chunks
#define CLEN    128    // L_SEQ / GCH
#define KSPLIT  16     // gemm1 K slices

// Buffers:
//   d_out (64 MB): gemm1 partials (16 x 2.6 MB) -> delta [L,D] -> output [L,D]
//   ws (26.2 MB): [0,655360) dbc fp32 (B/C cols); [655360,4849664) chunk partials;
//                 @4849664: dbch,dbcl,wdh,wdl (DSZ ushorts each);
//                 @5898240: winh,winl (655360 ushorts each)
#define DBC_SLICE 655360
#define PART_OFF  655360
#define BF_OFF    4849664   // float offset: dbch/dbcl/wdh/wdl
#define WIN_OFF   5898240   // float offset: winh/winl
#define DSZ       524288    // 4096*128
#define WSZ       655360    // 160*4096

typedef __attribute__((ext_vector_type(8))) short bf16x8;   // 8 bf16 = 4 VGPRs
typedef __attribute__((ext_vector_type(4))) float f32x4;

__device__ __forceinline__ float fast_exp2(float v) {
#if __has_builtin(__builtin_amdgcn_exp2f)
  return __builtin_amdgcn_exp2f(v);
#else
  return exp2f(v);
#endif
}

__device__ __forceinline__ unsigned short f2bf(float f) {     // RNE bf16
  uint32_t u = __float_as_uint(f);
  uint32_t r = (u + 0x7FFFu + ((u >> 16) & 1u)) >> 16;
  return (unsigned short)r;
}
__device__ __forceinline__ float bf2f(unsigned short b) {
  return __uint_as_float(((uint32_t)b) << 16);
}

// ---------------- generic fp32 -> bf16 hi/lo split (exact-size grids) ----------------
__global__ __launch_bounds__(256) void split_pair_kernel(const float* __restrict__ src,
                                                         unsigned short* __restrict__ dh,
                                                         unsigned short* __restrict__ dl) {
  const int i = (blockIdx.x * 256 + threadIdx.x) * 4;
  float4 a = *(const float4*)&src[i];
  float v[4] = {a.x, a.y, a.z, a.w};
  ushort4 h, lo;
  unsigned short* hp = (unsigned short*)&h;
  unsigned short* lp = (unsigned short*)&lo;
#pragma unroll
  for (int q = 0; q < 4; ++q) {
    hp[q] = f2bf(v[q]);
    lp[q] = f2bf(v[q] - bf2f(hp[q]));
  }
  *(ushort4*)&dh[i] = h;
  *(ushort4*)&dl[i] = lo;
}

// ---- GEMM1 via bf16x3 MFMA: parts[ks][l,j] = sum_{k in slice} x[l,k]*W_in[j,k] ----
// grid 1024 = 64 m-tiles (64 rows) x 16 K-slices (256 K). 4 waves; wave = 16 rows x 160 cols.
// x converted to bf16 hi/lo on the fly (each element touched by exactly one wave);
// W_in pre-split (winh/winl, L2-resident). No LDS, no barriers.
// A-frag: lane l -> row=l&15, k=(l>>4)*8+j. C/D: row=(l>>4)*4+r, col=l&15 [m89].
__global__ __launch_bounds__(256) void gemm1_kernel(const float* __restrict__ x,
                                                    const unsigned short* __restrict__ winh,
                                                    const unsigned short* __restrict__ winl,
                                                    float* __restrict__ parts) {
  const int t  = threadIdx.x;
  const int w  = t >> 6, l = t & 63;
  const int lr = l & 15;               // A-row / B-col / D-col
  const int lk = l >> 4;               // k-group 0..3
  const int mt = blockIdx.x >> 4;
  const int ks = blockIdx.x & 15;
  const int row = mt * 64 + w * 16 + lr;          // this lane's A row
  const int kb  = ks * 256;

  f32x4 acc[10];
#pragma unroll
  for (int j = 0; j < 10; ++j) acc[j] = (f32x4){0.f, 0.f, 0.f, 0.f};

#pragma unroll
  for (int kc = 0; kc < 8; ++kc) {
    const int k0 = kb + kc * 32 + lk * 8;
    // ---- A: load 8 fp32 of x, split to bf16 hi/lo in-register ----
    float4 xa0 = *(const float4*)&x[row * 4096 + k0];
    float4 xa1 = *(const float4*)&x[row * 4096 + k0 + 4];
    float va[8] = {xa0.x, xa0.y, xa0.z, xa0.w, xa1.x, xa1.y, xa1.z, xa1.w};
    bf16x8 ah, al_;
#pragma unroll
    for (int q = 0; q < 8; ++q) {
      unsigned short hq = f2bf(va[q]);
      ah[q]  = (short)hq;
      al_[q] = (short)f2bf(va[q] - bf2f(hq));
    }
    // ---- B: 10 column-tiles from pre-split W_in; 3-term MFMA ----
#pragma unroll
    for (int j = 0; j < 10; ++j) {
      const int col = j * 16 + lr;
      bf16x8 bh = *(const bf16x8*)&winh[col * 4096 + k0];
      bf16x8 bl = *(const bf16x8*)&winl[col * 4096 + k0];
      acc[j] = __builtin_amdgcn_mfma_f32_16x16x32_bf16(ah,  bh, acc[j], 0, 0, 0);
      acc[j] = __builtin_amdgcn_mfma_f32_16x16x32_bf16(ah,  bl, acc[j], 0, 0, 0);
      acc[j] = __builtin_amdgcn_mfma_f32_16x16x32_bf16(al_, bh, acc[j], 0, 0, 0);
    }
  }

  float* outp = parts + ks * DBC_SLICE;
  const int r0 = mt * 64 + w * 16 + lk * 4;       // D rows for this lane
#pragma unroll
  for (int j = 0; j < 10; ++j)
#pragma unroll
    for (int r = 0; r < 4; ++r)
      outp[(r0 + r) * NCOL + j * 16 + lr] = acc[j][r];
}

// ------- reduce 16 K-slices; delta cols -> bf16 hi/lo split, B/C cols -> fp32 dbc -------
__global__ __launch_bounds__(256) void reduce_dbc_kernel(const float* __restrict__ parts,
                                                         float* __restrict__ dbc,
                                                         unsigned short* __restrict__ dbch,
                                                         unsigned short* __restrict__ dbcl) {
  const int i = (blockIdx.x * 256 + threadIdx.x) * 4;  // grid 640 -> 655360
  float4 a = *(const float4*)&parts[i];
#pragma unroll
  for (int s = 1; s < KSPLIT; ++s) {
    float4 b = *(const float4*)&parts[(size_t)s * DBC_SLICE + i];
    a.x += b.x; a.y += b.y; a.z += b.z; a.w += b.w;
  }
  const int row = i / NCOL;
  const int col = i - row * NCOL;      // multiple of 4; quad never crosses a row
  if (col < RNK) {                     // delta part -> bf16 split only
    float v[4] = {a.x, a.y, a.z, a.w};
    ushort4 h, lo;
    unsigned short* hp = (unsigned short*)&h;
    unsigned short* lp = (unsigned short*)&lo;
#pragma unroll
    for (int q = 0; q < 4; ++q) {
      hp[q] = f2bf(v[q]);
      lp[q] = f2bf(v[q] - bf2f(hp[q]));
    }
    *(ushort4*)&dbch[row * RNK + col] = h;
    *(ushort4*)&dbcl[row * RNK + col] = lo;
  } else {                             // B/C part -> fp32 (consumed by scans)
    *(float4*)&dbc[i] = a;
  }
}

// ---- GEMM2 via bf16x3 MFMA (validated R10): delta = softplus(dbc @ Wd^T) ----
__global__ __launch_bounds__(256) void gemm2_kernel(const unsigned short* __restrict__ dbch,
                                                    const unsigned short* __restrict__ dbcl,
                                                    const unsigned short* __restrict__ Wdh,
                                                    const unsigned short* __restrict__ Wdl,
                                                    float* __restrict__ delta_out) {
  const int t  = threadIdx.x;
  const int w  = t >> 6, l = t & 63;
  const int lr = l & 15;
  const int lk = l >> 4;
  const int mt = blockIdx.x & 63, nt = blockIdx.x >> 6;
  const int wr = w >> 1, wc = w & 1;
  const int m0 = mt * 64 + wr * 32;
  const int n0 = nt * 128 + wc * 64;

  f32x4 acc[2][4];
#pragma unroll
  for (int i = 0; i < 2; ++i)
#pragma unroll
    for (int j = 0; j < 4; ++j)
      acc[i][j] = (f32x4){0.f, 0.f, 0.f, 0.f};

#pragma unroll
  for (int ks = 0; ks < 4; ++ks) {
    const int k0 = ks * 32 + lk * 8;
    bf16x8 ah[2], al_[2], bh[4], bl[4];
#pragma unroll
    for (int i = 0; i < 2; ++i) {
      ah[i]  = *(const bf16x8*)&dbch[(m0 + i * 16 + lr) * RNK + k0];
      al_[i] = *(const bf16x8*)&dbcl[(m0 + i * 16 + lr) * RNK + k0];
    }
#pragma unroll
    for (int j = 0; j < 4; ++j) {
      bh[j] = *(const bf16x8*)&Wdh[(n0 + j * 16 + lr) * RNK + k0];
      bl[j] = *(const bf16x8*)&Wdl[(n0 + j * 16 + lr) * RNK + k0];
    }
#pragma unroll
    for (int i = 0; i < 2; ++i)
#pragma unroll
      for (int j = 0; j < 4; ++j) {
        acc[i][j] = __builtin_amdgcn_mfma_f32_16x16x32_bf16(ah[i],  bh[j], acc[i][j], 0, 0, 0);
        acc[i][j] = __builtin_amdgcn_mfma_f32_16x16x32_bf16(ah[i],  bl[j], acc[i][j], 0, 0, 0);
        acc[i][j] = __builtin_amdgcn_mfma_f32_16x16x32_bf16(al_[i], bh[j], acc[i][j], 0, 0, 0);
      }
  }

#pragma unroll
  for (int i = 0; i < 2; ++i)
#pragma unroll
    for (int j = 0; j < 4; ++j)
#pragma unroll
      for (int r = 0; r < 4; ++r) {
        const int row = m0 + i * 16 + lk * 4 + r;
        const int col = n0 + j * 16 + lr;
        float v = acc[i][j][r];
        float sp = (v > 20.f) ? v : log1pf(__expf(v));   // stable softplus
        delta_out[row * 4096 + col] = sp;
      }
}

// ---------------- scan pass 1 (unchanged) ----------------
__global__ __launch_bounds__(256) void scan1_kernel(const float* __restrict__ delta,
                                                    const float* __restrict__ x,
                                                    const float* __restrict__ A_log,
                                                    const float* __restrict__ dbc,
                                                    float* __restrict__ part) {
  __shared__ float Bs[CLEN][NS];
  const int t = threadIdx.x;
  const int d = blockIdx.x * 256 + t;
  const int g = blockIdx.y;
  const int l0 = g * CLEN;
#pragma unroll
  for (int i = 0; i < 8; ++i) {
    int f = t + i * 256;
    int l = f >> 4, n = f & 15;
    Bs[l][n] = dbc[(l0 + l) * NCOL + RNK + n];
  }
  __syncthreads();

  float al2[NS];
#pragma unroll
  for (int n = 0; n < NS; ++n) al2[n] = -expf(A_log[d * NS + n]) * 1.44269504f;
  bool uni = true;
#pragma unroll
  for (int n = 1; n < NS; ++n) uni = uni && (al2[n] == al2[0]);

  float h[NS], P[NS];
#pragma unroll
  for (int n = 0; n < NS; ++n) { h[n] = 0.f; P[n] = 1.f; }

  if (uni) {
    const float a0 = al2[0];
    float Ps = 1.f;
    for (int l = 0; l < CLEN; ++l) {
      float dv = delta[(l0 + l) * 4096 + d];
      float xv = x[(l0 + l) * 4096 + d];
      float dx = dv * xv;
      float dA = fast_exp2(dv * a0);
      Ps *= dA;
      const float4* br = (const float4*)Bs[l];
      float4 b0 = br[0], b1 = br[1], b2 = br[2], b3 = br[3];
      h[0]  = fmaf(dA, h[0],  dx * b0.x); h[1]  = fmaf(dA, h[1],  dx * b0.y);
      h[2]  = fmaf(dA, h[2],  dx * b0.z); h[3]  = fmaf(dA, h[3],  dx * b0.w);
      h[4]  = fmaf(dA, h[4],  dx * b1.x); h[5]  = fmaf(dA, h[5],  dx * b1.y);
      h[6]  = fmaf(dA, h[6],  dx * b1.z); h[7]  = fmaf(dA, h[7],  dx * b1.w);
      h[8]  = fmaf(dA, h[8],  dx * b2.x); h[9]  = fmaf(dA, h[9],  dx * b2.y);
      h[10] = fmaf(dA, h[10], dx * b2.z); h[11] = fmaf(dA, h[11], dx * b2.w);
      h[12] = fmaf(dA, h[12], dx * b3.x); h[13] = fmaf(dA, h[13], dx * b3.y);
      h[14] = fmaf(dA, h[14], dx * b3.z); h[15] = fmaf(dA, h[15], dx * b3.w);
    }
#pragma unroll
    for (int n = 0; n < NS; ++n) P[n] = Ps;
  } else {
    for (int l = 0; l < CLEN; ++l) {
      float dv = delta[(l0 + l) * 4096 + d];
      float xv = x[(l0 + l) * 4096 + d];
      float dx = dv * xv;
#pragma unroll
      for (int n = 0; n < NS; ++n) {
        float dA = fast_exp2(dv * al2[n]);
        h[n] = fmaf(dA, h[n], dx * Bs[l][n]);
        P[n] *= dA;
      }
    }
  }
  float* pg = part + (size_t)g * 32 * 4096;
#pragma unroll
  for (int n = 0; n < NS; ++n) {
    pg[n * 4096 + d] = P[n];
    pg[(NS + n) * 4096 + d] = h[n];
  }
}

// ---------------- scan pass 2 (unchanged) ----------------
__global__ __launch_bounds__(256) void scan2_kernel(float* __restrict__ part) {
  const int idx = blockIdx.x * 256 + threadIdx.x;
  const int d = idx & 4095;
  const int n = idx >> 12;
  float h = 0.f;
  for (int g = 0; g < GCH; ++g) {
    float* pg = part + (size_t)g * 32 * 4096;
    float Pv = pg[n * 4096 + d];
    float Hv = pg[(NS + n) * 4096 + d];
    float nh = fmaf(Pv, h, Hv);
    pg[n * 4096 + d] = h;
    h = nh;
  }
}

// ---------------- scan pass 3 (unchanged) ----------------
__global__ __launch_bounds__(256) void scan3_kernel(float* io,
                                                    const float* __restrict__ x,
                                                    const float* __restrict__ A_log,
                                                    const float* __restrict__ dbc,
                                                    const float* __restrict__ Dvec,
                                                    const float* __restrict__ part) {
  __shared__ float Bs[CLEN][NS];
  __shared__ float Cs[CLEN][NS];
  const int t = threadIdx.x;
  const int d = blockIdx.x * 256 + t;
  const int g = blockIdx.y;
  const int l0 = g * CLEN;
#pragma unroll
  for (int i = 0; i < 8; ++i) {
    int f = t + i * 256;
    int l = f >> 4, n = f & 15;
    Bs[l][n] = dbc[(l0 + l) * NCOL + RNK + n];
    Cs[l][n] = dbc[(l0 + l) * NCOL + RNK + NS + n];
  }
  __syncthreads();

  float al2[NS];
#pragma unroll
  for (int n = 0; n < NS; ++n) al2[n] = -expf(A_log[d * NS + n]) * 1.44269504f;
  bool uni = true;
#pragma unroll
  for (int n = 1; n < NS; ++n) uni = uni && (al2[n] == al2[0]);

  float h[NS];
  const float* pg = part + (size_t)g * 32 * 4096;
#pragma unroll
  for (int n = 0; n < NS; ++n) h[n] = pg[n * 4096 + d];
  const float Dd = Dvec[d];

  if (uni) {
    const float a0 = al2[0];
    for (int l = 0; l < CLEN; ++l) {
      float dv = io[(size_t)(l0 + l) * 4096 + d];
      float xv = x[(l0 + l) * 4096 + d];
      float dx = dv * xv;
      float dA = fast_exp2(dv * a0);
      const float4* br = (const float4*)Bs[l];
      const float4* cr = (const float4*)Cs[l];
      float4 b0 = br[0], b1 = br[1], b2 = br[2], b3 = br[3];
      float4 c0 = cr[0], c1 = cr[1], c2 = cr[2], c3 = cr[3];
      float y = 0.f;
      h[0]  = fmaf(dA, h[0],  dx * b0.x); y = fmaf(h[0],  c0.x, y);
      h[1]  = fmaf(dA, h[1],  dx * b0.y); y = fmaf(h[1],  c0.y, y);
      h[2]  = fmaf(dA, h[2],  dx * b0.z); y = fmaf(h[2],  c0.z, y);
      h[3]  = fmaf(dA, h[3],  dx * b0.w); y = fmaf(h[3],  c0.w, y);
      h[4]  = fmaf(dA, h[4],  dx * b1.x); y = fmaf(h[4],  c1.x, y);
      h[5]  = fmaf(dA, h[5],  dx * b1.y); y = fmaf(h[5],  c1.y, y);
      h[6]  = fmaf(dA, h[6],  dx * b1.z); y = fmaf(h[6],  c1.z, y);
      h[7]  = fmaf(dA, h[7],  dx * b1.w); y = fmaf(h[7],  c1.w, y);
      h[8]  = fmaf(dA, h[8],  dx * b2.x); y = fmaf(h[8],  c2.x, y);
      h[9]  = fmaf(dA, h[9],  dx * b2.y); y = fmaf(h[9],  c2.y, y);
      h[10] = fmaf(dA, h[10], dx * b2.z); y = fmaf(h[10], c2.z, y);
      h[11] = fmaf(dA, h[11], dx * b2.w); y = fmaf(h[11], c2.w, y);
      h[12] = fmaf(dA, h[12], dx * b3.x); y = fmaf(h[12], c3.x, y);
      h[13] = fmaf(dA, h[13], dx * b3.y); y = fmaf(h[13], c3.y, y);
      h[14] = fmaf(dA, h[14], dx * b3.z); y = fmaf(h[14], c3.z, y);
      h[15] = fmaf(dA, h[15], dx * b3.w); y = fmaf(h[15], c3.w, y);
      io[(size_t)(l0 + l) * 4096 + d] = fmaf(xv, Dd, y);
    }
  } else {
    for (int l = 0; l < CLEN; ++l) {
      float dv = io[(size_t)(l0 + l) * 4096 + d];
      float xv = x[(l0 + l) * 4096 + d];
      float dx = dv * xv;
      float y = 0.f;
#pragma unroll
      for (int n = 0; n < NS; ++n) {
        float dA = fast_exp2(dv * al2[n]);
        h[n] = fmaf(dA, h[n], dx * Bs[l][n]);
        y = fmaf(h[n], Cs[l][n], y);
      }
      io[(size_t)(l0 + l) * 4096 + d] = fmaf(xv, Dd, y);
    }
  }
}

extern "C" void kernel_launch(void* const* d_in, const int* in_sizes, int n_in,
                              void* d_out, int out_size, void* d_ws, size_t ws_size,
                              hipStream_t stream) {
  const float* x    = (const float*)d_in[0];
  const float* Win  = (const float*)d_in[1];
  const float* Wd   = (const float*)d_in[2];
  const float* Alog = (const float*)d_in[3];
  const float* Dv   = (const float*)d_in[4];
  float* out = (float*)d_out;          // gemm1 partials -> delta -> output
  float* ws  = (float*)d_ws;           // 26.2 MB
  float* dbc  = ws;
  float* part = ws + PART_OFF;
  unsigned short* dbch = (unsigned short*)(ws + BF_OFF);
  unsigned short* dbcl = dbch + DSZ;
  unsigned short* wdh  = dbcl + DSZ;
  unsigned short* wdl  = wdh + DSZ;
  unsigned short* winh = (unsigned short*)(ws + WIN_OFF);
  unsigned short* winl = winh + WSZ;

  split_pair_kernel<<<640, 256, 0, stream>>>(Win, winh, winl);     // 160x4096
  split_pair_kernel<<<512, 256, 0, stream>>>(Wd, wdh, wdl);        // 4096x128
  gemm1_kernel<<<1024, 256, 0, stream>>>(x, winh, winl, out);      // partials -> d_out
  reduce_dbc_kernel<<<640, 256, 0, stream>>>(out, dbc, dbch, dbcl);
  gemm2_kernel<<<2048, 256, 0, stream>>>(dbch, dbcl, wdh, wdl, out);  // delta -> d_out
  scan1_kernel<<<dim3(16, 32), 256, 0, stream>>>(out, x, Alog, dbc, part);
  scan2_kernel<<<256, 256, 0, stream>>>(part);
  scan3_kernel<<<dim3(16, 32), 256, 0, stream>>>(out, x, Alog, dbc, Dv, part);
}

// Round 12
// 370.361 us; speedup vs baseline: 1.8186x; 1.0094x over previous
//
#include <hip/hip_runtime.h>
#include <math.h>
#include <stdint.h>

// Problem constants (fixed by the reference)
#define L_SEQ   4096
#define DI      4096   // d_inner
#define RNK     128    // dt_rank
#define NS      16     // d_state
#define NCOL    160    // dt_rank + 2*d_state
#define KSPLIT  16     // gemm1 K slices

// Workspace layout (floats):
//   [0, 655360)          : dbc fp32 (B/C cols consumed by scans)
//   [655360, ...)        : part  [GCH][32][4096]  (GCH=64 -> 36.2 MB total; GCH=32 -> 19.4 MB)
//   bf16 staging arrays OVERLAP the part region (all dead before scan1 writes part):
//     @655360: dbch,dbcl,wdh,wdl (DSZ ushorts each = 1,048,576 floats)
//     then winh,winl (WSZ ushorts each = 655,360 floats) -> ends at 2,359,296 < part end
//   d_out (64 MB): gemm1 partials (16 x 2.6 MB) -> delta [L,D] -> output [L,D]
#define DBC_SLICE 655360
#define PART_OFF  655360
#define DSZ       524288    // 4096*128
#define WSZ       655360    // 160*4096
#define PART_STRIDE (32 * 4096)

typedef __attribute__((ext_vector_type(8))) short bf16x8;
typedef __attribute__((ext_vector_type(4))) float f32x4;

__device__ __forceinline__ float fast_exp2(float v) {
#if __has_builtin(__builtin_amdgcn_exp2f)
  return __builtin_amdgcn_exp2f(v);
#else
  return exp2f(v);
#endif
}

__device__ __forceinline__ unsigned short f2bf(float f) {     // RNE bf16
  uint32_t u = __float_as_uint(f);
  uint32_t r = (u + 0x7FFFu + ((u >> 16) & 1u)) >> 16;
  return (unsigned short)r;
}
__device__ __forceinline__ float bf2f(unsigned short b) {
  return __uint_as_float(((uint32_t)b) << 16);
}

// ---------------- generic fp32 -> bf16 hi/lo split ----------------
__global__ __launch_bounds__(256) void split_pair_kernel(const float* __restrict__ src,
                                                         unsigned short* __restrict__ dh,
                                                         unsigned short* __restrict__ dl) {
  const int i = (blockIdx.x * 256 + threadIdx.x) * 4;
  float4 a = *(const float4*)&src[i];
  float v[4] = {a.x, a.y, a.z, a.w};
  ushort4 h, lo;
  unsigned short* hp = (unsigned short*)&h;
  unsigned short* lp = (unsigned short*)&lo;
#pragma unroll
  for (int q = 0; q < 4; ++q) {
    hp[q] = f2bf(v[q]);
    lp[q] = f2bf(v[q] - bf2f(hp[q]));
  }
  *(ushort4*)&dh[i] = h;
  *(ushort4*)&dl[i] = lo;
}

// ---- GEMM1 via bf16x3 MFMA. grid 2048 = 128 m-tiles (32 rows) x 16 K-slices (256 K).
// 4 waves = 2(row)x2(col); wave = 16 rows x 80 cols (5 j-tiles). 8 blocks/CU -> 32 waves/CU.
// x converted to bf16 hi/lo on the fly; W_in pre-split (L2-resident). No LDS, no barriers.
__global__ __launch_bounds__(256) void gemm1_kernel(const float* __restrict__ x,
                                                    const unsigned short* __restrict__ winh,
                                                    const unsigned short* __restrict__ winl,
                                                    float* __restrict__ parts) {
  const int t  = threadIdx.x;
  const int w  = t >> 6, l = t & 63;
  const int lr = l & 15;               // A-row / B-col / D-col
  const int lk = l >> 4;               // k-group 0..3
  const int mt = blockIdx.x >> 4;      // 0..127
  const int ks = blockIdx.x & 15;
  const int wr = w >> 1, wc = w & 1;
  const int row = mt * 32 + wr * 16 + lr;
  const int c0  = wc * 80;
  const int kb  = ks * 256;

  f32x4 acc[5];
#pragma unroll
  for (int j = 0; j < 5; ++j) acc[j] = (f32x4){0.f, 0.f, 0.f, 0.f};

#pragma unroll
  for (int kc = 0; kc < 8; ++kc) {
    const int k0 = kb + kc * 32 + lk * 8;
    float4 xa0 = *(const float4*)&x[row * 4096 + k0];
    float4 xa1 = *(const float4*)&x[row * 4096 + k0 + 4];
    float va[8] = {xa0.x, xa0.y, xa0.z, xa0.w, xa1.x, xa1.y, xa1.z, xa1.w};
    bf16x8 ah, al_;
#pragma unroll
    for (int q = 0; q < 8; ++q) {
      unsigned short hq = f2bf(va[q]);
      ah[q]  = (short)hq;
      al_[q] = (short)f2bf(va[q] - bf2f(hq));
    }
#pragma unroll
    for (int j = 0; j < 5; ++j) {
      const int col = c0 + j * 16 + lr;
      bf16x8 bh = *(const bf16x8*)&winh[col * 4096 + k0];
      bf16x8 bl = *(const bf16x8*)&winl[col * 4096 + k0];
      acc[j] = __builtin_amdgcn_mfma_f32_16x16x32_bf16(ah,  bh, acc[j], 0, 0, 0);
      acc[j] = __builtin_amdgcn_mfma_f32_16x16x32_bf16(ah,  bl, acc[j], 0, 0, 0);
      acc[j] = __builtin_amdgcn_mfma_f32_16x16x32_bf16(al_, bh, acc[j], 0, 0, 0);
    }
  }

  float* outp = parts + ks * DBC_SLICE;
  const int r0 = mt * 32 + wr * 16 + lk * 4;
#pragma unroll
  for (int j = 0; j < 5; ++j)
#pragma unroll
    for (int r = 0; r < 4; ++r)
      outp[(r0 + r) * NCOL + c0 + j * 16 + lr] = acc[j][r];
}

// ------- reduce 16 K-slices; delta cols -> bf16 hi/lo split, B/C cols -> fp32 dbc -------
__global__ __launch_bounds__(256) void reduce_dbc_kernel(const float* __restrict__ parts,
                                                         float* __restrict__ dbc,
                                                         unsigned short* __restrict__ dbch,
                                                         unsigned short* __restrict__ dbcl) {
  const int i = (blockIdx.x * 256 + threadIdx.x) * 4;  // grid 640 -> 655360
  float4 a = *(const float4*)&parts[i];
#pragma unroll
  for (int s = 1; s < KSPLIT; ++s) {
    float4 b = *(const float4*)&parts[(size_t)s * DBC_SLICE + i];
    a.x += b.x; a.y += b.y; a.z += b.z; a.w += b.w;
  }
  const int row = i / NCOL;
  const int col = i - row * NCOL;      // quad never crosses a row (160 % 4 == 0)
  if (col < RNK) {
    float v[4] = {a.x, a.y, a.z, a.w};
    ushort4 h, lo;
    unsigned short* hp = (unsigned short*)&h;
    unsigned short* lp = (unsigned short*)&lo;
#pragma unroll
    for (int q = 0; q < 4; ++q) {
      hp[q] = f2bf(v[q]);
      lp[q] = f2bf(v[q] - bf2f(hp[q]));
    }
    *(ushort4*)&dbch[row * RNK + col] = h;
    *(ushort4*)&dbcl[row * RNK + col] = lo;
  } else {
    *(float4*)&dbc[i] = a;
  }
}

// ---- GEMM2 via bf16x3 MFMA (validated R10): delta = softplus(dbc @ Wd^T) ----
__global__ __launch_bounds__(256) void gemm2_kernel(const unsigned short* __restrict__ dbch,
                                                    const unsigned short* __restrict__ dbcl,
                                                    const unsigned short* __restrict__ Wdh,
                                                    const unsigned short* __restrict__ Wdl,
                                                    float* __restrict__ delta_out) {
  const int t  = threadIdx.x;
  const int w  = t >> 6, l = t & 63;
  const int lr = l & 15;
  const int lk = l >> 4;
  const int mt = blockIdx.x & 63, nt = blockIdx.x >> 6;
  const int wr = w >> 1, wc = w & 1;
  const int m0 = mt * 64 + wr * 32;
  const int n0 = nt * 128 + wc * 64;

  f32x4 acc[2][4];
#pragma unroll
  for (int i = 0; i < 2; ++i)
#pragma unroll
    for (int j = 0; j < 4; ++j)
      acc[i][j] = (f32x4){0.f, 0.f, 0.f, 0.f};

#pragma unroll
  for (int ks = 0; ks < 4; ++ks) {
    const int k0 = ks * 32 + lk * 8;
    bf16x8 ah[2], al_[2], bh[4], bl[4];
#pragma unroll
    for (int i = 0; i < 2; ++i) {
      ah[i]  = *(const bf16x8*)&dbch[(m0 + i * 16 + lr) * RNK + k0];
      al_[i] = *(const bf16x8*)&dbcl[(m0 + i * 16 + lr) * RNK + k0];
    }
#pragma unroll
    for (int j = 0; j < 4; ++j) {
      bh[j] = *(const bf16x8*)&Wdh[(n0 + j * 16 + lr) * RNK + k0];
      bl[j] = *(const bf16x8*)&Wdl[(n0 + j * 16 + lr) * RNK + k0];
    }
#pragma unroll
    for (int i = 0; i < 2; ++i)
#pragma unroll
      for (int j = 0; j < 4; ++j) {
        acc[i][j] = __builtin_amdgcn_mfma_f32_16x16x32_bf16(ah[i],  bh[j], acc[i][j], 0, 0, 0);
        acc[i][j] = __builtin_amdgcn_mfma_f32_16x16x32_bf16(ah[i],  bl[j], acc[i][j], 0, 0, 0);
        acc[i][j] = __builtin_amdgcn_mfma_f32_16x16x32_bf16(al_[i], bh[j], acc[i][j], 0, 0, 0);
      }
  }

#pragma unroll
  for (int i = 0; i < 2; ++i)
#pragma unroll
    for (int j = 0; j < 4; ++j)
#pragma unroll
      for (int r = 0; r < 4; ++r) {
        const int row = m0 + i * 16 + lk * 4 + r;
        const int col = n0 + j * 16 + lr;
        float v = acc[i][j][r];
        float sp = (v > 20.f) ? v : log1pf(__expf(v));
        delta_out[row * 4096 + col] = sp;
      }
}

// ---------------- scan pass 1, templated on chunk length ----------------
template <int CLEN_T>
__global__ __launch_bounds__(256) void scan1_kernel(const float* __restrict__ delta,
                                                    const float* __restrict__ x,
                                                    const float* __restrict__ A_log,
                                                    const float* __restrict__ dbc,
                                                    float* __restrict__ part) {
  __shared__ float Bs[CLEN_T][NS];
  const int t = threadIdx.x;
  const int d = blockIdx.x * 256 + t;
  const int g = blockIdx.y;
  const int l0 = g * CLEN_T;
#pragma unroll
  for (int i = 0; i < CLEN_T * NS / 256; ++i) {
    int f = t + i * 256;
    int l = f >> 4, n = f & 15;
    Bs[l][n] = dbc[(l0 + l) * NCOL + RNK + n];
  }
  __syncthreads();

  float al2[NS];
#pragma unroll
  for (int n = 0; n < NS; ++n) al2[n] = -expf(A_log[d * NS + n]) * 1.44269504f;
  bool uni = true;
#pragma unroll
  for (int n = 1; n < NS; ++n) uni = uni && (al2[n] == al2[0]);

  float h[NS], P[NS];
#pragma unroll
  for (int n = 0; n < NS; ++n) { h[n] = 0.f; P[n] = 1.f; }

  if (uni) {
    const float a0 = al2[0];
    float Ps = 1.f;
    for (int l = 0; l < CLEN_T; ++l) {
      float dv = delta[(l0 + l) * 4096 + d];
      float xv = x[(l0 + l) * 4096 + d];
      float dx = dv * xv;
      float dA = fast_exp2(dv * a0);
      Ps *= dA;
      const float4* br = (const float4*)Bs[l];
      float4 b0 = br[0], b1 = br[1], b2 = br[2], b3 = br[3];
      h[0]  = fmaf(dA, h[0],  dx * b0.x); h[1]  = fmaf(dA, h[1],  dx * b0.y);
      h[2]  = fmaf(dA, h[2],  dx * b0.z); h[3]  = fmaf(dA, h[3],  dx * b0.w);
      h[4]  = fmaf(dA, h[4],  dx * b1.x); h[5]  = fmaf(dA, h[5],  dx * b1.y);
      h[6]  = fmaf(dA, h[6],  dx * b1.z); h[7]  = fmaf(dA, h[7],  dx * b1.w);
      h[8]  = fmaf(dA, h[8],  dx * b2.x); h[9]  = fmaf(dA, h[9],  dx * b2.y);
      h[10] = fmaf(dA, h[10], dx * b2.z); h[11] = fmaf(dA, h[11], dx * b2.w);
      h[12] = fmaf(dA, h[12], dx * b3.x); h[13] = fmaf(dA, h[13], dx * b3.y);
      h[14] = fmaf(dA, h[14], dx * b3.z); h[15] = fmaf(dA, h[15], dx * b3.w);
    }
#pragma unroll
    for (int n = 0; n < NS; ++n) P[n] = Ps;
  } else {
    for (int l = 0; l < CLEN_T; ++l) {
      float dv = delta[(l0 + l) * 4096 + d];
      float xv = x[(l0 + l) * 4096 + d];
      float dx = dv * xv;
#pragma unroll
      for (int n = 0; n < NS; ++n) {
        float dA = fast_exp2(dv * al2[n]);
        h[n] = fmaf(dA, h[n], dx * Bs[l][n]);
        P[n] *= dA;
      }
    }
  }
  float* pg = part + (size_t)g * PART_STRIDE;
#pragma unroll
  for (int n = 0; n < NS; ++n) {
    pg[n * 4096 + d] = P[n];
    pg[(NS + n) * 4096 + d] = h[n];
  }
}

// ---------------- scan pass 2: combine chunks (chunk count runtime) ----------------
__global__ __launch_bounds__(256) void scan2_kernel(float* __restrict__ part, int gch) {
  const int idx = blockIdx.x * 256 + threadIdx.x;
  const int d = idx & 4095;
  const int n = idx >> 12;
  float h = 0.f;
  for (int g = 0; g < gch; ++g) {
    float* pg = part + (size_t)g * PART_STRIDE;
    float Pv = pg[n * 4096 + d];
    float Hv = pg[(NS + n) * 4096 + d];
    float nh = fmaf(Pv, h, Hv);
    pg[n * 4096 + d] = h;   // h_in for chunk g
    h = nh;
  }
}

// ---------------- scan pass 3, templated on chunk length ----------------
template <int CLEN_T>
__global__ __launch_bounds__(256) void scan3_kernel(float* io,
                                                    const float* __restrict__ x,
                                                    const float* __restrict__ A_log,
                                                    const float* __restrict__ dbc,
                                                    const float* __restrict__ Dvec,
                                                    const float* __restrict__ part) {
  __shared__ float Bs[CLEN_T][NS];
  __shared__ float Cs[CLEN_T][NS];
  const int t = threadIdx.x;
  const int d = blockIdx.x * 256 + t;
  const int g = blockIdx.y;
  const int l0 = g * CLEN_T;
#pragma unroll
  for (int i = 0; i < CLEN_T * NS / 256; ++i) {
    int f = t + i * 256;
    int l = f >> 4, n = f & 15;
    Bs[l][n] = dbc[(l0 + l) * NCOL + RNK + n];
    Cs[l][n] = dbc[(l0 + l) * NCOL + RNK + NS + n];
  }
  __syncthreads();

  float al2[NS];
#pragma unroll
  for (int n = 0; n < NS; ++n) al2[n] = -expf(A_log[d * NS + n]) * 1.44269504f;
  bool uni = true;
#pragma unroll
  for (int n = 1; n < NS; ++n) uni = uni && (al2[n] == al2[0]);

  float h[NS];
  const float* pg = part + (size_t)g * PART_STRIDE;
#pragma unroll
  for (int n = 0; n < NS; ++n) h[n] = pg[n * 4096 + d];
  const float Dd = Dvec[d];

  if (uni) {
    const float a0 = al2[0];
    for (int l = 0; l < CLEN_T; ++l) {
      float dv = io[(size_t)(l0 + l) * 4096 + d];
      float xv = x[(l0 + l) * 4096 + d];
      float dx = dv * xv;
      float dA = fast_exp2(dv * a0);
      const float4* br = (const float4*)Bs[l];
      const float4* cr = (const float4*)Cs[l];
      float4 b0 = br[0], b1 = br[1], b2 = br[2], b3 = br[3];
      float4 c0 = cr[0], c1 = cr[1], c2 = cr[2], c3 = cr[3];
      float y = 0.f;
      h[0]  = fmaf(dA, h[0],  dx * b0.x); y = fmaf(h[0],  c0.x, y);
      h[1]  = fmaf(dA, h[1],  dx * b0.y); y = fmaf(h[1],  c0.y, y);
      h[2]  = fmaf(dA, h[2],  dx * b0.z); y = fmaf(h[2],  c0.z, y);
      h[3]  = fmaf(dA, h[3],  dx * b0.w); y = fmaf(h[3],  c0.w, y);
      h[4]  = fmaf(dA, h[4],  dx * b1.x); y = fmaf(h[4],  c1.x, y);
      h[5]  = fmaf(dA, h[5],  dx * b1.y); y = fmaf(h[5],  c1.y, y);
      h[6]  = fmaf(dA, h[6],  dx * b1.z); y = fmaf(h[6],  c1.z, y);
      h[7]  = fmaf(dA, h[7],  dx * b1.w); y = fmaf(h[7],  c1.w, y);
      h[8]  = fmaf(dA, h[8],  dx * b2.x); y = fmaf(h[8],  c2.x, y);
      h[9]  = fmaf(dA, h[9],  dx * b2.y); y = fmaf(h[9],  c2.y, y);
      h[10] = fmaf(dA, h[10], dx * b2.z); y = fmaf(h[10], c2.z, y);
      h[11] = fmaf(dA, h[11], dx * b2.w); y = fmaf(h[11], c2.w, y);
      h[12] = fmaf(dA, h[12], dx * b3.x); y = fmaf(h[12], c3.x, y);
      h[13] = fmaf(dA, h[13], dx * b3.y); y = fmaf(h[13], c3.y, y);
      h[14] = fmaf(dA, h[14], dx * b3.z); y = fmaf(h[14], c3.z, y);
      h[15] = fmaf(dA, h[15], dx * b3.w); y = fmaf(h[15], c3.w, y);
      io[(size_t)(l0 + l) * 4096 + d] = fmaf(xv, Dd, y);
    }
  } else {
    for (int l = 0; l < CLEN_T; ++l) {
      float dv = io[(size_t)(l0 + l) * 4096 + d];
      float xv = x[(l0 + l) * 4096 + d];
      float dx = dv * xv;
      float y = 0.f;
#pragma unroll
      for (int n = 0; n < NS; ++n) {
        float dA = fast_exp2(dv * al2[n]);
        h[n] = fmaf(dA, h[n], dx * Bs[l][n]);
        y = fmaf(h[n], Cs[l][n], y);
      }
      io[(size_t)(l0 + l) * 4096 + d] = fmaf(xv, Dd, y);
    }
  }
}

extern "C" void kernel_launch(void* const* d_in, const int* in_sizes, int n_in,
                              void* d_out, int out_size, void* d_ws, size_t ws_size,
                              hipStream_t stream) {
  const float* x    = (const float*)d_in[0];
  const float* Win  = (const float*)d_in[1];
  const float* Wd   = (const float*)d_in[2];
  const float* Alog = (const float*)d_in[3];
  const float* Dv   = (const float*)d_in[4];
  float* out = (float*)d_out;          // gemm1 partials -> delta -> output
  float* ws  = (float*)d_ws;
  float* dbc  = ws;
  float* part = ws + PART_OFF;
  // bf16 staging arrays live INSIDE the part region (dead before scan1 writes part)
  unsigned short* dbch = (unsigned short*)(ws + PART_OFF);
  unsigned short* dbcl = dbch + DSZ;
  unsigned short* wdh  = dbcl + DSZ;
  unsigned short* wdl  = wdh + DSZ;
  unsigned short* winh = wdl + DSZ;
  unsigned short* winl = winh + WSZ;

  // GCH=64 needs PART_OFF + 64*PART_STRIDE floats = 36.2 MB; else fall back to GCH=32.
  const bool big = ws_size >= (size_t)(PART_OFF + 64 * PART_STRIDE) * sizeof(float);

  split_pair_kernel<<<640, 256, 0, stream>>>(Win, winh, winl);     // 160x4096
  split_pair_kernel<<<512, 256, 0, stream>>>(Wd, wdh, wdl);        // 4096x128
  gemm1_kernel<<<2048, 256, 0, stream>>>(x, winh, winl, out);      // partials -> d_out
  reduce_dbc_kernel<<<640, 256, 0, stream>>>(out, dbc, dbch, dbcl);
  gemm2_kernel<<<2048, 256, 0, stream>>>(dbch, dbcl, wdh, wdl, out);  // delta -> d_out
  if (big) {
    scan1_kernel<64><<<dim3(16, 64), 256, 0, stream>>>(out, x, Alog, dbc, part);
    scan2_kernel<<<256, 256, 0, stream>>>(part, 64);
    scan3_kernel<64><<<dim3(16, 64), 256, 0, stream>>>(out, x, Alog, dbc, Dv, part);
  } else {
    scan1_kernel<128><<<dim3(16, 32), 256, 0, stream>>>(out, x, Alog, dbc, part);
    scan2_kernel<<<256, 256, 0, stream>>>(part, 32);
    scan3_kernel<128><<<dim3(16, 32), 256, 0, stream>>>(out, x, Alog, dbc, Dv, part);
  }
}

// Round 13
// 303.262 us; speedup vs baseline: 2.2210x; 1.2213x over previous
//
#include <hip/hip_runtime.h>
#include <math.h>
#include <stdint.h>

// Problem constants (fixed by the reference)
#define L_SEQ   4096
#define DI      4096   // d_inner
#define RNK     128    // dt_rank
#define NS      16     // d_state
#define NCOL    160    // dt_rank + 2*d_state
#define KSPLIT  16     // gemm1 K slices

// Workspace layout (floats):
//   [0, 655360)   : dbc fp32 (B/C cols consumed by scans)
//   [655360, ...) : part [GCH][32][4096] (GCH=64 -> 36.2 MB; GCH=32 -> 19.4 MB fallback)
//   bf16 staging arrays OVERLAP the part region (dead before scan1 writes part)
//   d_out (64 MB): gemm1 partials (16 x 2.6 MB) -> delta [L,D] -> output [L,D]
#define DBC_SLICE 655360
#define PART_OFF  655360
#define DSZ       524288    // 4096*128
#define WSZ       655360    // 160*4096
#define PART_STRIDE (32 * 4096)

typedef __attribute__((ext_vector_type(8))) short bf16x8;
typedef __attribute__((ext_vector_type(4))) float f32x4;

__device__ __forceinline__ float fast_exp2(float v) {
#if __has_builtin(__builtin_amdgcn_exp2f)
  return __builtin_amdgcn_exp2f(v);
#else
  return exp2f(v);
#endif
}

__device__ __forceinline__ unsigned short f2bf(float f) {     // RNE bf16
  uint32_t u = __float_as_uint(f);
  uint32_t r = (u + 0x7FFFu + ((u >> 16) & 1u)) >> 16;
  return (unsigned short)r;
}
__device__ __forceinline__ float bf2f(unsigned short b) {
  return __uint_as_float(((uint32_t)b) << 16);
}

// ---------------- generic fp32 -> bf16 hi/lo split ----------------
__global__ __launch_bounds__(256) void split_pair_kernel(const float* __restrict__ src,
                                                         unsigned short* __restrict__ dh,
                                                         unsigned short* __restrict__ dl) {
  const int i = (blockIdx.x * 256 + threadIdx.x) * 4;
  float4 a = *(const float4*)&src[i];
  float v[4] = {a.x, a.y, a.z, a.w};
  ushort4 h, lo;
  unsigned short* hp = (unsigned short*)&h;
  unsigned short* lp = (unsigned short*)&lo;
#pragma unroll
  for (int q = 0; q < 4; ++q) {
    hp[q] = f2bf(v[q]);
    lp[q] = f2bf(v[q] - bf2f(hp[q]));
  }
  *(ushort4*)&dh[i] = h;
  *(ushort4*)&dl[i] = lo;
}

// ---- GEMM1 via bf16x3 MFMA with LDS staging (coalesced loads, no gathers) ----
// grid 1024 = 64 m-tiles (64 rows) x 16 K-slices (256 K; 8 chunks of 32).
// 4 waves; wave = 16 rows x 160 cols (10 j-tiles), acc 10 x f32x4.
// LDS: ushort [2 (hi/lo)][224 (64 x-rows | 160 w-cols)][40 (32k + pad)] = 35840 B.
// Stage phase: x coalesced float4 (+in-thread bf16 split); W coalesced 16B.
// Compute: fragments via 16B ds_read_b128 (<=2-way banks, stride 40 ushorts).
__global__ __launch_bounds__(256) void gemm1_kernel(const float* __restrict__ x,
                                                    const unsigned short* __restrict__ winh,
                                                    const unsigned short* __restrict__ winl,
                                                    float* __restrict__ parts) {
  __shared__ unsigned short xw[2][224][40];
  const int t  = threadIdx.x;
  const int w  = t >> 6, l = t & 63;
  const int lr = l & 15;               // A-row / B-col / D-col
  const int lk = l >> 4;               // k-group 0..3
  const int mt = blockIdx.x >> 4;
  const int ks = blockIdx.x & 15;
  const int row0 = mt * 64;
  const int kbase0 = ks * 256;

  f32x4 acc[10];
#pragma unroll
  for (int j = 0; j < 10; ++j) acc[j] = (f32x4){0.f, 0.f, 0.f, 0.f};

  for (int kc = 0; kc < 8; ++kc) {
    const int kb = kbase0 + kc * 32;
    // ---- stage x: 64 rows x 32 k fp32, coalesced; split to bf16 hi/lo on write ----
#pragma unroll
    for (int i = 0; i < 2; ++i) {
      const int f = t + i * 256;       // 0..511
      const int row = f >> 3, q = f & 7;
      float4 v = *(const float4*)&x[(row0 + row) * 4096 + kb + q * 4];
      float va[4] = {v.x, v.y, v.z, v.w};
      ushort4 h, lo;
      unsigned short* hp = (unsigned short*)&h;
      unsigned short* lp = (unsigned short*)&lo;
#pragma unroll
      for (int qq = 0; qq < 4; ++qq) {
        hp[qq] = f2bf(va[qq]);
        lp[qq] = f2bf(va[qq] - bf2f(hp[qq]));
      }
      *(ushort4*)&xw[0][row][q * 4] = h;    // 8B ds_write, aligned (80*row+8q)
      *(ushort4*)&xw[1][row][q * 4] = lo;
    }
    // ---- stage W: 160 cols x 32 k, hi+lo, coalesced 16B chunks ----
#pragma unroll
    for (int i = 0; i < 5; ++i) {
      const int f = t + i * 256;       // 0..1279
      const int ar = (f >= 640);
      const int g  = f - ar * 640;     // 0..639
      const int col = g >> 2, q = g & 3;
      const unsigned short* src = ar ? winl : winh;
      uint4 v = *(const uint4*)&src[col * 4096 + kb + q * 8];
      *(uint4*)&xw[ar][64 + col][q * 8] = v;   // 16B ds_write, aligned
    }
    __syncthreads();
    // ---- compute: fragments from LDS, 30 MFMAs ----
    const int rl = w * 16 + lr;        // this lane's A row (local)
    bf16x8 ah  = *(const bf16x8*)&xw[0][rl][lk * 8];
    bf16x8 al_ = *(const bf16x8*)&xw[1][rl][lk * 8];
#pragma unroll
    for (int j = 0; j < 10; ++j) {
      const int cl = 64 + j * 16 + lr;
      bf16x8 bh = *(const bf16x8*)&xw[0][cl][lk * 8];
      bf16x8 bl = *(const bf16x8*)&xw[1][cl][lk * 8];
      acc[j] = __builtin_amdgcn_mfma_f32_16x16x32_bf16(ah,  bh, acc[j], 0, 0, 0);
      acc[j] = __builtin_amdgcn_mfma_f32_16x16x32_bf16(ah,  bl, acc[j], 0, 0, 0);
      acc[j] = __builtin_amdgcn_mfma_f32_16x16x32_bf16(al_, bh, acc[j], 0, 0, 0);
    }
    __syncthreads();
  }

  float* outp = parts + ks * DBC_SLICE;
  const int r0 = mt * 64 + w * 16 + lk * 4;
#pragma unroll
  for (int j = 0; j < 10; ++j)
#pragma unroll
    for (int r = 0; r < 4; ++r)
      outp[(r0 + r) * NCOL + j * 16 + lr] = acc[j][r];
}

// ------- reduce 16 K-slices; delta cols -> bf16 hi/lo split, B/C cols -> fp32 dbc -------
__global__ __launch_bounds__(256) void reduce_dbc_kernel(const float* __restrict__ parts,
                                                         float* __restrict__ dbc,
                                                         unsigned short* __restrict__ dbch,
                                                         unsigned short* __restrict__ dbcl) {
  const int i = (blockIdx.x * 256 + threadIdx.x) * 4;  // grid 640 -> 655360
  float4 a = *(const float4*)&parts[i];
#pragma unroll
  for (int s = 1; s < KSPLIT; ++s) {
    float4 b = *(const float4*)&parts[(size_t)s * DBC_SLICE + i];
    a.x += b.x; a.y += b.y; a.z += b.z; a.w += b.w;
  }
  const int row = i / NCOL;
  const int col = i - row * NCOL;
  if (col < RNK) {
    float v[4] = {a.x, a.y, a.z, a.w};
    ushort4 h, lo;
    unsigned short* hp = (unsigned short*)&h;
    unsigned short* lp = (unsigned short*)&lo;
#pragma unroll
    for (int q = 0; q < 4; ++q) {
      hp[q] = f2bf(v[q]);
      lp[q] = f2bf(v[q] - bf2f(hp[q]));
    }
    *(ushort4*)&dbch[row * RNK + col] = h;
    *(ushort4*)&dbcl[row * RNK + col] = lo;
  } else {
    *(float4*)&dbc[i] = a;
  }
}

// ---- GEMM2 via bf16x3 MFMA (validated R10): delta = softplus(dbc @ Wd^T) ----
__global__ __launch_bounds__(256) void gemm2_kernel(const unsigned short* __restrict__ dbch,
                                                    const unsigned short* __restrict__ dbcl,
                                                    const unsigned short* __restrict__ Wdh,
                                                    const unsigned short* __restrict__ Wdl,
                                                    float* __restrict__ delta_out) {
  const int t  = threadIdx.x;
  const int w  = t >> 6, l = t & 63;
  const int lr = l & 15;
  const int lk = l >> 4;
  const int mt = blockIdx.x & 63, nt = blockIdx.x >> 6;
  const int wr = w >> 1, wc = w & 1;
  const int m0 = mt * 64 + wr * 32;
  const int n0 = nt * 128 + wc * 64;

  f32x4 acc[2][4];
#pragma unroll
  for (int i = 0; i < 2; ++i)
#pragma unroll
    for (int j = 0; j < 4; ++j)
      acc[i][j] = (f32x4){0.f, 0.f, 0.f, 0.f};

#pragma unroll
  for (int ks = 0; ks < 4; ++ks) {
    const int k0 = ks * 32 + lk * 8;
    bf16x8 ah[2], al_[2], bh[4], bl[4];
#pragma unroll
    for (int i = 0; i < 2; ++i) {
      ah[i]  = *(const bf16x8*)&dbch[(m0 + i * 16 + lr) * RNK + k0];
      al_[i] = *(const bf16x8*)&dbcl[(m0 + i * 16 + lr) * RNK + k0];
    }
#pragma unroll
    for (int j = 0; j < 4; ++j) {
      bh[j] = *(const bf16x8*)&Wdh[(n0 + j * 16 + lr) * RNK + k0];
      bl[j] = *(const bf16x8*)&Wdl[(n0 + j * 16 + lr) * RNK + k0];
    }
#pragma unroll
    for (int i = 0; i < 2; ++i)
#pragma unroll
      for (int j = 0; j < 4; ++j) {
        acc[i][j] = __builtin_amdgcn_mfma_f32_16x16x32_bf16(ah[i],  bh[j], acc[i][j], 0, 0, 0);
        acc[i][j] = __builtin_amdgcn_mfma_f32_16x16x32_bf16(ah[i],  bl[j], acc[i][j], 0, 0, 0);
        acc[i][j] = __builtin_amdgcn_mfma_f32_16x16x32_bf16(al_[i], bh[j], acc[i][j], 0, 0, 0);
      }
  }

#pragma unroll
  for (int i = 0; i < 2; ++i)
#pragma unroll
    for (int j = 0; j < 4; ++j)
#pragma unroll
      for (int r = 0; r < 4; ++r) {
        const int row = m0 + i * 16 + lk * 4 + r;
        const int col = n0 + j * 16 + lr;
        float v = acc[i][j][r];
        float sp = (v > 20.f) ? v : log1pf(__expf(v));
        delta_out[row * 4096 + col] = sp;
      }
}

// ---------------- scan pass 1, templated on chunk length ----------------
template <int CLEN_T>
__global__ __launch_bounds__(256) void scan1_kernel(const float* __restrict__ delta,
                                                    const float* __restrict__ x,
                                                    const float* __restrict__ A_log,
                                                    const float* __restrict__ dbc,
                                                    float* __restrict__ part) {
  __shared__ float Bs[CLEN_T][NS];
  const int t = threadIdx.x;
  const int d = blockIdx.x * 256 + t;
  const int g = blockIdx.y;
  const int l0 = g * CLEN_T;
#pragma unroll
  for (int i = 0; i < CLEN_T * NS / 256; ++i) {
    int f = t + i * 256;
    int l = f >> 4, n = f & 15;
    Bs[l][n] = dbc[(l0 + l) * NCOL + RNK + n];
  }
  __syncthreads();

  float al2[NS];
#pragma unroll
  for (int n = 0; n < NS; ++n) al2[n] = -expf(A_log[d * NS + n]) * 1.44269504f;
  bool uni = true;
#pragma unroll
  for (int n = 1; n < NS; ++n) uni = uni && (al2[n] == al2[0]);

  float h[NS], P[NS];
#pragma unroll
  for (int n = 0; n < NS; ++n) { h[n] = 0.f; P[n] = 1.f; }

  if (uni) {
    const float a0 = al2[0];
    float Ps = 1.f;
    for (int l = 0; l < CLEN_T; ++l) {
      float dv = delta[(l0 + l) * 4096 + d];
      float xv = x[(l0 + l) * 4096 + d];
      float dx = dv * xv;
      float dA = fast_exp2(dv * a0);
      Ps *= dA;
      const float4* br = (const float4*)Bs[l];
      float4 b0 = br[0], b1 = br[1], b2 = br[2], b3 = br[3];
      h[0]  = fmaf(dA, h[0],  dx * b0.x); h[1]  = fmaf(dA, h[1],  dx * b0.y);
      h[2]  = fmaf(dA, h[2],  dx * b0.z); h[3]  = fmaf(dA, h[3],  dx * b0.w);
      h[4]  = fmaf(dA, h[4],  dx * b1.x); h[5]  = fmaf(dA, h[5],  dx * b1.y);
      h[6]  = fmaf(dA, h[6],  dx * b1.z); h[7]  = fmaf(dA, h[7],  dx * b1.w);
      h[8]  = fmaf(dA, h[8],  dx * b2.x); h[9]  = fmaf(dA, h[9],  dx * b2.y);
      h[10] = fmaf(dA, h[10], dx * b2.z); h[11] = fmaf(dA, h[11], dx * b2.w);
      h[12] = fmaf(dA, h[12], dx * b3.x); h[13] = fmaf(dA, h[13], dx * b3.y);
      h[14] = fmaf(dA, h[14], dx * b3.z); h[15] = fmaf(dA, h[15], dx * b3.w);
    }
#pragma unroll
    for (int n = 0; n < NS; ++n) P[n] = Ps;
  } else {
    for (int l = 0; l < CLEN_T; ++l) {
      float dv = delta[(l0 + l) * 4096 + d];
      float xv = x[(l0 + l) * 4096 + d];
      float dx = dv * xv;
#pragma unroll
      for (int n = 0; n < NS; ++n) {
        float dA = fast_exp2(dv * al2[n]);
        h[n] = fmaf(dA, h[n], dx * Bs[l][n]);
        P[n] *= dA;
      }
    }
  }
  float* pg = part + (size_t)g * PART_STRIDE;
#pragma unroll
  for (int n = 0; n < NS; ++n) {
    pg[n * 4096 + d] = P[n];
    pg[(NS + n) * 4096 + d] = h[n];
  }
}

// ---------------- scan pass 2: combine chunks (chunk count runtime) ----------------
__global__ __launch_bounds__(256) void scan2_kernel(float* __restrict__ part, int gch) {
  const int idx = blockIdx.x * 256 + threadIdx.x;
  const int d = idx & 4095;
  const int n = idx >> 12;
  float h = 0.f;
  for (int g = 0; g < gch; ++g) {
    float* pg = part + (size_t)g * PART_STRIDE;
    float Pv = pg[n * 4096 + d];
    float Hv = pg[(NS + n) * 4096 + d];
    float nh = fmaf(Pv, h, Hv);
    pg[n * 4096 + d] = h;   // h_in for chunk g
    h = nh;
  }
}

// ---------------- scan pass 3, templated on chunk length ----------------
template <int CLEN_T>
__global__ __launch_bounds__(256) void scan3_kernel(float* io,
                                                    const float* __restrict__ x,
                                                    const float* __restrict__ A_log,
                                                    const float* __restrict__ dbc,
                                                    const float* __restrict__ Dvec,
                                                    const float* __restrict__ part) {
  __shared__ float Bs[CLEN_T][NS];
  __shared__ float Cs[CLEN_T][NS];
  const int t = threadIdx.x;
  const int d = blockIdx.x * 256 + t;
  const int g = blockIdx.y;
  const int l0 = g * CLEN_T;
#pragma unroll
  for (int i = 0; i < CLEN_T * NS / 256; ++i) {
    int f = t + i * 256;
    int l = f >> 4, n = f & 15;
    Bs[l][n] = dbc[(l0 + l) * NCOL + RNK + n];
    Cs[l][n] = dbc[(l0 + l) * NCOL + RNK + NS + n];
  }
  __syncthreads();

  float al2[NS];
#pragma unroll
  for (int n = 0; n < NS; ++n) al2[n] = -expf(A_log[d * NS + n]) * 1.44269504f;
  bool uni = true;
#pragma unroll
  for (int n = 1; n < NS; ++n) uni = uni && (al2[n] == al2[0]);

  float h[NS];
  const float* pg = part + (size_t)g * PART_STRIDE;
#pragma unroll
  for (int n = 0; n < NS; ++n) h[n] = pg[n * 4096 + d];
  const float Dd = Dvec[d];

  if (uni) {
    const float a0 = al2[0];
    for (int l = 0; l < CLEN_T; ++l) {
      float dv = io[(size_t)(l0 + l) * 4096 + d];
      float xv = x[(l0 + l) * 4096 + d];
      float dx = dv * xv;
      float dA = fast_exp2(dv * a0);
      const float4* br = (const float4*)Bs[l];
      const float4* cr = (const float4*)Cs[l];
      float4 b0 = br[0], b1 = br[1], b2 = br[2], b3 = br[3];
      float4 c0 = cr[0], c1 = cr[1], c2 = cr[2], c3 = cr[3];
      float y = 0.f;
      h[0]  = fmaf(dA, h[0],  dx * b0.x); y = fmaf(h[0],  c0.x, y);
      h[1]  = fmaf(dA, h[1],  dx * b0.y); y = fmaf(h[1],  c0.y, y);
      h[2]  = fmaf(dA, h[2],  dx * b0.z); y = fmaf(h[2],  c0.z, y);
      h[3]  = fmaf(dA, h[3],  dx * b0.w); y = fmaf(h[3],  c0.w, y);
      h[4]  = fmaf(dA, h[4],  dx * b1.x); y = fmaf(h[4],  c1.x, y);
      h[5]  = fmaf(dA, h[5],  dx * b1.y); y = fmaf(h[5],  c1.y, y);
      h[6]  = fmaf(dA, h[6],  dx * b1.z); y = fmaf(h[6],  c1.z, y);
      h[7]  = fmaf(dA, h[7],  dx * b1.w); y = fmaf(h[7],  c1.w, y);
      h[8]  = fmaf(dA, h[8],  dx * b2.x); y = fmaf(h[8],  c2.x, y);
      h[9]  = fmaf(dA, h[9],  dx * b2.y); y = fmaf(h[9],  c2.y, y);
      h[10] = fmaf(dA, h[10], dx * b2.z); y = fmaf(h[10], c2.z, y);
      h[11] = fmaf(dA, h[11], dx * b2.w); y = fmaf(h[11], c2.w, y);
      h[12] = fmaf(dA, h[12], dx * b3.x); y = fmaf(h[12], c3.x, y);
      h[13] = fmaf(dA, h[13], dx * b3.y); y = fmaf(h[13], c3.y, y);
      h[14] = fmaf(dA, h[14], dx * b3.z); y = fmaf(h[14], c3.z, y);
      h[15] = fmaf(dA, h[15], dx * b3.w); y = fmaf(h[15], c3.w, y);
      io[(size_t)(l0 + l) * 4096 + d] = fmaf(xv, Dd, y);
    }
  } else {
    for (int l = 0; l < CLEN_T; ++l) {
      float dv = io[(size_t)(l0 + l) * 4096 + d];
      float xv = x[(l0 + l) * 4096 + d];
      float dx = dv * xv;
      float y = 0.f;
#pragma unroll
      for (int n = 0; n < NS; ++n) {
        float dA = fast_exp2(dv * al2[n]);
        h[n] = fmaf(dA, h[n], dx * Bs[l][n]);
        y = fmaf(h[n], Cs[l][n], y);
      }
      io[(size_t)(l0 + l) * 4096 + d] = fmaf(xv, Dd, y);
    }
  }
}

extern "C" void kernel_launch(void* const* d_in, const int* in_sizes, int n_in,
                              void* d_out, int out_size, void* d_ws, size_t ws_size,
                              hipStream_t stream) {
  const float* x    = (const float*)d_in[0];
  const float* Win  = (const float*)d_in[1];
  const float* Wd   = (const float*)d_in[2];
  const float* Alog = (const float*)d_in[3];
  const float* Dv   = (const float*)d_in[4];
  float* out = (float*)d_out;          // gemm1 partials -> delta -> output
  float* ws  = (float*)d_ws;
  float* dbc  = ws;
  float* part = ws + PART_OFF;
  // bf16 staging arrays live INSIDE the part region (dead before scan1 writes part)
  unsigned short* dbch = (unsigned short*)(ws + PART_OFF);
  unsigned short* dbcl = dbch + DSZ;
  unsigned short* wdh  = dbcl + DSZ;
  unsigned short* wdl  = wdh + DSZ;
  unsigned short* winh = wdl + DSZ;
  unsigned short* winl = winh + WSZ;

  const bool big = ws_size >= (size_t)(PART_OFF + 64 * PART_STRIDE) * sizeof(float);

  split_pair_kernel<<<640, 256, 0, stream>>>(Win, winh, winl);     // 160x4096
  split_pair_kernel<<<512, 256, 0, stream>>>(Wd, wdh, wdl);        // 4096x128
  gemm1_kernel<<<1024, 256, 0, stream>>>(x, winh, winl, out);      // partials -> d_out
  reduce_dbc_kernel<<<640, 256, 0, stream>>>(out, dbc, dbch, dbcl);
  gemm2_kernel<<<2048, 256, 0, stream>>>(dbch, dbcl, wdh, wdl, out);  // delta -> d_out
  if (big) {
    scan1_kernel<64><<<dim3(16, 64), 256, 0, stream>>>(out, x, Alog, dbc, part);
    scan2_kernel<<<256, 256, 0, stream>>>(part, 64);
    scan3_kernel<64><<<dim3(16, 64), 256, 0, stream>>>(out, x, Alog, dbc, Dv, part);
  } else {
    scan1_kernel<128><<<dim3(16, 32), 256, 0, stream>>>(out, x, Alog, dbc, part);
    scan2_kernel<<<256, 256, 0, stream>>>(part, 32);
    scan3_kernel<128><<<dim3(16, 32), 256, 0, stream>>>(out, x, Alog, dbc, Dv, part);
  }
}